// Round 1
// baseline (246.780 us; speedup 1.0000x reference)
//
#include <hip/hip_runtime.h>

typedef unsigned short u16;
typedef short short8 __attribute__((ext_vector_type(8)));
typedef float f32x4 __attribute__((ext_vector_type(4)));

#define N_B 2
#define N_L 2048
#define N_D 1024
#define N_H 16
#define N_KVH 4
#define HDIM 64
#define WINDOW 1024

__device__ __forceinline__ u16 f2bf(float f) {
  unsigned u = __builtin_bit_cast(unsigned, f);
  u = u + 0x7fffu + ((u >> 16) & 1u);
  return (u16)(u >> 16);
}

// ---------------- prep kernels ----------------

__global__ void convert_x(const float* __restrict__ x, u16* __restrict__ xb) {
  int idx = (blockIdx.x * 256 + threadIdx.x) * 4;
  float4 f = *(const float4*)&x[idx];
  u16 o[4] = {f2bf(f.x), f2bf(f.y), f2bf(f.z), f2bf(f.w)};
  *(ushort4*)&xb[idx] = *(ushort4*)o;
}

// src [1024][srcN] fp32 -> dst [srcN][1024] bf16 (dst pre-offset by caller)
__global__ void transpose_w(const float* __restrict__ src, u16* __restrict__ dst, int srcN) {
  __shared__ float t[32][33];
  int n0 = blockIdx.x * 32, k0 = blockIdx.y * 32;
  int lx = threadIdx.x, ly = threadIdx.y;  // (32,8)
#pragma unroll
  for (int q = 0; q < 4; q++)
    t[ly + 8 * q][lx] = src[(k0 + ly + 8 * q) * srcN + n0 + lx];
  __syncthreads();
#pragma unroll
  for (int q = 0; q < 4; q++)
    dst[(n0 + ly + 8 * q) * 1024 + k0 + lx] = f2bf(t[lx][ly + 8 * q]);
}

__global__ void rope_table(float* __restrict__ rc, float* __restrict__ rs) {
  int idx = blockIdx.x * 256 + threadIdx.x;  // 2048*32
  int i = idx >> 5, j = idx & 31;
  float inv = powf(10000.0f, -(float)j * (1.0f / 32.0f));
  float ang = (float)i * inv;
  rc[idx] = cosf(ang);
  rs[idx] = sinf(ang);
}

// ---------------- GEMM: C[M,N] = A[M,K=1024] * Bt[N,K=1024]^T ----------------
// MODE 0: qkv projection, RoPE epilogue, scatter to Q/K/V bf16
// MODE 1: out projection, fp32 store

template <int MODE>
__global__ __launch_bounds__(256) void gemm_kernel(
    const u16* __restrict__ A, const u16* __restrict__ Bt,
    u16* __restrict__ qo, u16* __restrict__ ko, u16* __restrict__ vo,
    float* __restrict__ fo, const float* __restrict__ rc, const float* __restrict__ rs) {
  __shared__ u16 a_s[128 * 40];
  __shared__ u16 b_s[128 * 40];
  int tid = threadIdx.x;
  int w = tid >> 6, lane = tid & 63, quad = lane >> 4, r = lane & 15;
  int wm = w >> 1, wn = w & 1;
  int m0 = blockIdx.y * 128, n0 = blockIdx.x * 128;

  f32x4 zero4 = {0.f, 0.f, 0.f, 0.f};
  f32x4 acc[4][4];
#pragma unroll
  for (int a_ = 0; a_ < 4; a_++)
#pragma unroll
    for (int b_ = 0; b_ < 4; b_++) acc[a_][b_] = zero4;

  for (int kt = 0; kt < 32; ++kt) {
#pragma unroll
    for (int c = tid; c < 512; c += 256) {
      int row = c >> 2, k8 = (c & 3) << 3;
      *(uint4*)&a_s[row * 40 + k8] = *(const uint4*)&A[(m0 + row) * 1024 + kt * 32 + k8];
      *(uint4*)&b_s[row * 40 + k8] = *(const uint4*)&Bt[(n0 + row) * 1024 + kt * 32 + k8];
    }
    __syncthreads();
    short8 af[4], bfr[4];
#pragma unroll
    for (int tm = 0; tm < 4; tm++)
      af[tm] = *(const short8*)&a_s[(wm * 64 + tm * 16 + r) * 40 + quad * 8];
#pragma unroll
    for (int tn = 0; tn < 4; tn++)
      bfr[tn] = *(const short8*)&b_s[(wn * 64 + tn * 16 + r) * 40 + quad * 8];
#pragma unroll
    for (int tm = 0; tm < 4; tm++)
#pragma unroll
      for (int tn = 0; tn < 4; tn++)
        acc[tm][tn] = __builtin_amdgcn_mfma_f32_16x16x32_bf16(af[tm], bfr[tn], acc[tm][tn], 0, 0, 0);
    __syncthreads();
  }

  int nbase = n0 + wn * 64;  // 64-aligned, uniform per wave
  if (MODE == 0) {
    if (nbase < 1024) {  // Q + RoPE
      int h = nbase >> 6;
#pragma unroll
      for (int tm = 0; tm < 4; tm++) {
#pragma unroll
        for (int reg = 0; reg < 4; reg++) {
          int m = m0 + wm * 64 + tm * 16 + quad * 4 + reg;
          int b = m >> 11, i = m & 2047;
          int base = ((b * N_H + h) * N_L + i) * HDIM;
#pragma unroll
          for (int tn = 0; tn < 2; tn++) {
            int dlo = tn * 16 + r;
            float c = rc[i * 32 + dlo], s = rs[i * 32 + dlo];
            float vlo = acc[tm][tn][reg], vhi = acc[tm][tn + 2][reg];
            qo[base + dlo] = f2bf(vlo * c - vhi * s);
            qo[base + dlo + 32] = f2bf(vhi * c + vlo * s);
          }
        }
      }
    } else if (nbase < 1280) {  // K + RoPE
      int h = (nbase - 1024) >> 6;
#pragma unroll
      for (int tm = 0; tm < 4; tm++) {
#pragma unroll
        for (int reg = 0; reg < 4; reg++) {
          int m = m0 + wm * 64 + tm * 16 + quad * 4 + reg;
          int b = m >> 11, i = m & 2047;
          int base = ((b * N_KVH + h) * N_L + i) * HDIM;
#pragma unroll
          for (int tn = 0; tn < 2; tn++) {
            int dlo = tn * 16 + r;
            float c = rc[i * 32 + dlo], s = rs[i * 32 + dlo];
            float vlo = acc[tm][tn][reg], vhi = acc[tm][tn + 2][reg];
            ko[base + dlo] = f2bf(vlo * c - vhi * s);
            ko[base + dlo + 32] = f2bf(vhi * c + vlo * s);
          }
        }
      }
    } else {  // V plain
      int h = (nbase - 1280) >> 6;
#pragma unroll
      for (int tm = 0; tm < 4; tm++) {
#pragma unroll
        for (int reg = 0; reg < 4; reg++) {
          int m = m0 + wm * 64 + tm * 16 + quad * 4 + reg;
          int b = m >> 11, i = m & 2047;
          int base = ((b * N_KVH + h) * N_L + i) * HDIM;
#pragma unroll
          for (int tn = 0; tn < 4; tn++)
            vo[base + tn * 16 + r] = f2bf(acc[tm][tn][reg]);
        }
      }
    }
  } else {  // MODE 1: fp32 store
#pragma unroll
    for (int tm = 0; tm < 4; tm++) {
#pragma unroll
      for (int reg = 0; reg < 4; reg++) {
        int m = m0 + wm * 64 + tm * 16 + quad * 4 + reg;
#pragma unroll
        for (int tn = 0; tn < 4; tn++)
          fo[m * 1024 + nbase + tn * 16 + r] = acc[tm][tn][reg];
      }
    }
  }
}

// ---------------- flash attention, sliding window, GQA ----------------
// grid (32 qblocks, 16 heads, 2 batch), 256 threads (4 waves x 16 q-rows)

__global__ __launch_bounds__(256) void attn_kernel(
    const u16* __restrict__ Q, const u16* __restrict__ K,
    const u16* __restrict__ V, u16* __restrict__ O) {
  __shared__ u16 k_s[64 * 72];   // [key][dim] padded
  __shared__ u16 vt_s[64 * 72];  // [dim][key] padded
  __shared__ u16 p_s[4 * 16 * 72];
  int tid = threadIdx.x, w = tid >> 6, lane = tid & 63, quad = lane >> 4, r = lane & 15;
  int qb = blockIdx.x, h = blockIdx.y, b = blockIdx.z;
  int i0 = qb * 64;
  int hk = h >> 2;

  const u16* qptr = Q + ((b * N_H + h) * N_L + i0 + w * 16 + r) * HDIM;
  short8 qf[2];
  qf[0] = *(const short8*)&qptr[quad * 8];
  qf[1] = *(const short8*)&qptr[32 + quad * 8];

  const u16* kbase = K + (b * N_KVH + hk) * N_L * HDIM;
  const u16* vbase = V + (b * N_KVH + hk) * N_L * HDIM;

  f32x4 zero4 = {0.f, 0.f, 0.f, 0.f};
  float m_r[4] = {-1e30f, -1e30f, -1e30f, -1e30f};
  float l_r[4] = {0.f, 0.f, 0.f, 0.f};
  f32x4 o_acc[4];
#pragma unroll
  for (int tn = 0; tn < 4; tn++) o_acc[tn] = zero4;

  int jt0 = (i0 >= WINDOW) ? ((i0 - (WINDOW - 1)) >> 6) : 0;
  int ibase = i0 + w * 16 + quad * 4;

  for (int jt = jt0; jt <= qb; ++jt) {
    int j0 = jt << 6;
    __syncthreads();
    // stage K tile [64][64] -> k_s[key*72 + dim]
#pragma unroll
    for (int c = tid; c < 512; c += 256) {
      int row = c >> 3, off = (c & 7) << 3;
      *(uint4*)&k_s[row * 72 + off] = *(const uint4*)&kbase[(j0 + row) * 64 + off];
    }
    // stage V transposed -> vt_s[dim*72 + key]
#pragma unroll
    for (int it = 0; it < 4; ++it) {
      int flat = it * 256 + tid;
      int key = flat >> 4, d4 = (flat & 15) << 2;
      uint2 tmp = *(const uint2*)&vbase[(j0 + key) * 64 + d4];
      u16* pv = (u16*)&tmp;
#pragma unroll
      for (int e = 0; e < 4; e++) vt_s[(d4 + e) * 72 + key] = pv[e];
    }
    __syncthreads();

    // S = Q K^T
    f32x4 s_acc[4];
#pragma unroll
    for (int tn = 0; tn < 4; tn++) s_acc[tn] = zero4;
#pragma unroll
    for (int ks = 0; ks < 2; ks++) {
#pragma unroll
      for (int tn = 0; tn < 4; tn++) {
        short8 kf = *(const short8*)&k_s[(tn * 16 + r) * 72 + ks * 32 + quad * 8];
        s_acc[tn] = __builtin_amdgcn_mfma_f32_16x16x32_bf16(qf[ks], kf, s_acc[tn], 0, 0, 0);
      }
    }

    // online softmax update
    float p[4][4];
#pragma unroll
    for (int reg = 0; reg < 4; reg++) {
      int i = ibase + reg;
      float sv[4];
#pragma unroll
      for (int tn = 0; tn < 4; tn++) {
        int j = j0 + tn * 16 + r;
        float s = s_acc[tn][reg] * 0.125f;
        bool ok = (j <= i) && (i - j < WINDOW);
        sv[tn] = ok ? s : -3.0e37f;
      }
      float tmax = fmaxf(fmaxf(sv[0], sv[1]), fmaxf(sv[2], sv[3]));
#pragma unroll
      for (int d = 1; d < 16; d <<= 1) tmax = fmaxf(tmax, __shfl_xor(tmax, d));
      float mnew = fmaxf(m_r[reg], tmax);
      float alpha = __expf(m_r[reg] - mnew);
      m_r[reg] = mnew;
      float rsum = 0.f;
#pragma unroll
      for (int tn = 0; tn < 4; tn++) {
        float pv_ = __expf(sv[tn] - mnew);
        p[tn][reg] = pv_;
        rsum += pv_;
      }
#pragma unroll
      for (int d = 1; d < 16; d <<= 1) rsum += __shfl_xor(rsum, d);
      l_r[reg] = l_r[reg] * alpha + rsum;
#pragma unroll
      for (int tn = 0; tn < 4; tn++) o_acc[tn][reg] *= alpha;
    }

    // P: C-layout -> A-layout via per-wave LDS round trip
    int base_p = w * 16 * 72;
#pragma unroll
    for (int tn = 0; tn < 4; tn++)
#pragma unroll
      for (int reg = 0; reg < 4; reg++)
        p_s[base_p + (quad * 4 + reg) * 72 + tn * 16 + r] = f2bf(p[tn][reg]);
    __syncthreads();

    // O += P V
#pragma unroll
    for (int ks = 0; ks < 2; ks++) {
      short8 pf = *(const short8*)&p_s[base_p + r * 72 + ks * 32 + quad * 8];
#pragma unroll
      for (int tn = 0; tn < 4; tn++) {
        short8 vf = *(const short8*)&vt_s[(tn * 16 + r) * 72 + ks * 32 + quad * 8];
        o_acc[tn] = __builtin_amdgcn_mfma_f32_16x16x32_bf16(pf, vf, o_acc[tn], 0, 0, 0);
      }
    }
  }

  // epilogue: O /= l, store to Ob[token][h*64+dim]
  int obase = (b * N_L + i0 + w * 16) * 1024 + h * 64;
#pragma unroll
  for (int reg = 0; reg < 4; reg++) {
    float inv = 1.0f / l_r[reg];
    int row = quad * 4 + reg;
#pragma unroll
    for (int tn = 0; tn < 4; tn++)
      O[obase + row * 1024 + tn * 16 + r] = f2bf(o_acc[tn][reg] * inv);
  }
}

// ---------------- launch ----------------

extern "C" void kernel_launch(void* const* d_in, const int* in_sizes, int n_in,
                              void* d_out, int out_size, void* d_ws, size_t ws_size,
                              hipStream_t stream) {
  const float* x = (const float*)d_in[0];
  const float* Wq = (const float*)d_in[1];
  const float* Wk = (const float*)d_in[2];
  const float* Wv = (const float*)d_in[3];
  const float* Wo = (const float*)d_in[4];
  float* out = (float*)d_out;
  char* ws = (char*)d_ws;

  u16* xb    = (u16*)(ws);                // 8 MB  [4096][1024]
  u16* wqkvT = (u16*)(ws + 0x800000);     // 3 MB  [1536][1024]
  u16* woT   = (u16*)(ws + 0xB00000);     // 2 MB  [1024][1024]
  u16* Qb    = (u16*)(ws + 0xD00000);     // 8 MB  [B][H][L][64]
  u16* Kb    = (u16*)(ws + 0x1500000);    // 2 MB  [B][KvH][L][64]
  u16* Vb    = (u16*)(ws + 0x1700000);    // 2 MB
  u16* Ob    = (u16*)(ws + 0x1900000);    // 8 MB  [4096][1024]
  float* rc  = (float*)(ws + 0x2100000);  // 256 KB [2048][32]
  float* rs  = (float*)(ws + 0x2140000);  // 256 KB

  convert_x<<<4096, 256, 0, stream>>>(x, xb);
  dim3 tb(32, 8);
  transpose_w<<<dim3(32, 32), tb, 0, stream>>>(Wq, wqkvT, 1024);
  transpose_w<<<dim3(8, 32), tb, 0, stream>>>(Wk, wqkvT + 1024 * 1024, 256);
  transpose_w<<<dim3(8, 32), tb, 0, stream>>>(Wv, wqkvT + 1280 * 1024, 256);
  transpose_w<<<dim3(32, 32), tb, 0, stream>>>(Wo, woT, 1024);
  rope_table<<<256, 256, 0, stream>>>(rc, rs);

  gemm_kernel<0><<<dim3(12, 32), 256, 0, stream>>>(xb, wqkvT, Qb, Kb, Vb, nullptr, rc, rs);
  attn_kernel<<<dim3(32, 16, 2), 256, 0, stream>>>(Qb, Kb, Vb, Ob);
  gemm_kernel<1><<<dim3(8, 32), 256, 0, stream>>>(Ob, woT, nullptr, nullptr, nullptr, out, nullptr, nullptr);
}

// Round 2
// 196.107 us; speedup vs baseline: 1.2584x; 1.2584x over previous
//
#include <hip/hip_runtime.h>

typedef unsigned short u16;
typedef unsigned int u32;
typedef short short8 __attribute__((ext_vector_type(8)));
typedef float f32x4 __attribute__((ext_vector_type(4)));

#define N_B 2
#define N_L 2048
#define N_D 1024
#define N_H 16
#define N_KVH 4
#define HDIM 64
#define WINDOW 1024

__device__ __forceinline__ u16 f2bf(float f) {
  unsigned u = __builtin_bit_cast(unsigned, f);
  u = u + 0x7fffu + ((u >> 16) & 1u);
  return (u16)(u >> 16);
}

union U2 {
  u16 h[4];
  uint2 v;
};

// async global->LDS, 16B per lane. LDS dest must be wave-uniform base + lane*16.
__device__ __forceinline__ void gl2lds16(const u16* g, u16* l) {
  __builtin_amdgcn_global_load_lds((const __attribute__((address_space(1))) void*)g,
                                   (__attribute__((address_space(3))) void*)l, 16, 0, 0);
}

// ---------------- prep kernels ----------------

__global__ void convert_x(const float* __restrict__ x, u16* __restrict__ xb) {
  int idx = (blockIdx.x * 256 + threadIdx.x) * 4;
  float4 f = *(const float4*)&x[idx];
  u16 o[4] = {f2bf(f.x), f2bf(f.y), f2bf(f.z), f2bf(f.w)};
  *(ushort4*)&xb[idx] = *(ushort4*)o;
}

// src [1024][srcN] fp32 -> dst [srcN][1024] bf16 (dst pre-offset by caller)
__global__ void transpose_w(const float* __restrict__ src, u16* __restrict__ dst, int srcN) {
  __shared__ float t[32][33];
  int n0 = blockIdx.x * 32, k0 = blockIdx.y * 32;
  int lx = threadIdx.x, ly = threadIdx.y;  // (32,8)
#pragma unroll
  for (int q = 0; q < 4; q++)
    t[ly + 8 * q][lx] = src[(k0 + ly + 8 * q) * srcN + n0 + lx];
  __syncthreads();
#pragma unroll
  for (int q = 0; q < 4; q++)
    dst[(n0 + ly + 8 * q) * 1024 + k0 + lx] = f2bf(t[lx][ly + 8 * q]);
}

__global__ void rope_table(float* __restrict__ rc, float* __restrict__ rs) {
  int idx = blockIdx.x * 256 + threadIdx.x;  // 2048*32
  int i = idx >> 5, j = idx & 31;
  float inv = powf(10000.0f, -(float)j * (1.0f / 32.0f));
  float ang = (float)i * inv;
  rc[idx] = cosf(ang);
  rs[idx] = sinf(ang);
}

// ---------------- GEMM: C[M,N] = A[M,K=1024] * Bt[N,K=1024]^T ----------------
// MODE 0: qkv projection; RoPE+scale epilogue for Q/K; V stored TRANSPOSED
//         globally as Vt[b][hkv][64][2048].
// MODE 1: out projection, fp32 store.

template <int MODE>
__global__ __launch_bounds__(256) void gemm_kernel(
    const u16* __restrict__ A, const u16* __restrict__ Bt,
    u16* __restrict__ qo, u16* __restrict__ ko, u16* __restrict__ vo,
    float* __restrict__ fo, const float* __restrict__ rc, const float* __restrict__ rs) {
  __shared__ u16 a_s[128 * 32];
  __shared__ u16 b_s[128 * 32];
  int tid = threadIdx.x;
  int w = tid >> 6, lane = tid & 63, quad = lane >> 4, r = lane & 15;
  int wm = w >> 1, wn = w & 1;
  int m0 = blockIdx.y * 128, n0 = blockIdx.x * 128;

  f32x4 zero4 = {0.f, 0.f, 0.f, 0.f};
  f32x4 acc[4][4];
#pragma unroll
  for (int a_ = 0; a_ < 4; a_++)
#pragma unroll
    for (int b_ = 0; b_ < 4; b_++) acc[a_][b_] = zero4;

  for (int kt = 0; kt < 32; ++kt) {
#pragma unroll
    for (int it = 0; it < 2; ++it) {
      int cc = it * 256 + tid;
      int row = cc >> 2, part = cc & 3;  // 32 elems/row = 4 chunks of 8
      gl2lds16(&A[(m0 + row) * 1024 + kt * 32 + part * 8], &a_s[cc * 8]);
      gl2lds16(&Bt[(n0 + row) * 1024 + kt * 32 + part * 8], &b_s[cc * 8]);
    }
    __syncthreads();
    short8 af[4], bfr[4];
#pragma unroll
    for (int tm = 0; tm < 4; tm++)
      af[tm] = *(const short8*)&a_s[(wm * 64 + tm * 16 + r) * 32 + quad * 8];
#pragma unroll
    for (int tn = 0; tn < 4; tn++)
      bfr[tn] = *(const short8*)&b_s[(wn * 64 + tn * 16 + r) * 32 + quad * 8];
#pragma unroll
    for (int tm = 0; tm < 4; tm++)
#pragma unroll
      for (int tn = 0; tn < 4; tn++)
        acc[tm][tn] = __builtin_amdgcn_mfma_f32_16x16x32_bf16(af[tm], bfr[tn], acc[tm][tn], 0, 0, 0);
    __syncthreads();
  }

  int nbase = n0 + wn * 64;  // 64-aligned, uniform per wave
  if constexpr (MODE == 0) {
    if (nbase < 1024) {  // Q + RoPE + 1/sqrt(d) scale
      int h = nbase >> 6;
#pragma unroll
      for (int tm = 0; tm < 4; tm++) {
#pragma unroll
        for (int reg = 0; reg < 4; reg++) {
          int m = m0 + wm * 64 + tm * 16 + quad * 4 + reg;
          int b = m >> 11, i = m & 2047;
          int base = ((b * N_H + h) * N_L + i) * HDIM;
#pragma unroll
          for (int tn = 0; tn < 2; tn++) {
            int dlo = tn * 16 + r;
            float c = rc[i * 32 + dlo], s = rs[i * 32 + dlo];
            float vlo = acc[tm][tn][reg], vhi = acc[tm][tn + 2][reg];
            qo[base + dlo] = f2bf((vlo * c - vhi * s) * 0.125f);
            qo[base + dlo + 32] = f2bf((vhi * c + vlo * s) * 0.125f);
          }
        }
      }
    } else if (nbase < 1280) {  // K + RoPE
      int h = (nbase - 1024) >> 6;
#pragma unroll
      for (int tm = 0; tm < 4; tm++) {
#pragma unroll
        for (int reg = 0; reg < 4; reg++) {
          int m = m0 + wm * 64 + tm * 16 + quad * 4 + reg;
          int b = m >> 11, i = m & 2047;
          int base = ((b * N_KVH + h) * N_L + i) * HDIM;
#pragma unroll
          for (int tn = 0; tn < 2; tn++) {
            int dlo = tn * 16 + r;
            float c = rc[i * 32 + dlo], s = rs[i * 32 + dlo];
            float vlo = acc[tm][tn][reg], vhi = acc[tm][tn + 2][reg];
            ko[base + dlo] = f2bf(vlo * c - vhi * s);
            ko[base + dlo + 32] = f2bf(vhi * c + vlo * s);
          }
        }
      }
    } else {  // V: transpose via LDS bounce -> Vt[b][hkv][64][2048]
      __shared__ u16 vs[4 * 64 * 72];
      int hkv = (nbase - 1280) >> 6;
      int bb = (m0 + wm * 64) >> 11;
      int tbase = (m0 + wm * 64) & 2047;
      u16* myvs = vs + w * 4608;
#pragma unroll
      for (int tm = 0; tm < 4; tm++) {
#pragma unroll
        for (int tn = 0; tn < 4; tn++) {
          U2 pk;
#pragma unroll
          for (int reg = 0; reg < 4; reg++) pk.h[reg] = f2bf(acc[tm][tn][reg]);
          *(uint2*)&myvs[(tn * 16 + r) * 72 + tm * 16 + quad * 4] = pk.v;
        }
      }
      __asm__ volatile("s_waitcnt lgkmcnt(0)" ::: "memory");  // wave-local LDS RAW
      u16* vtb = vo + (size_t)((bb * N_KVH + hkv) * 64) * 2048;
#pragma unroll
      for (int q2 = 0; q2 < 8; ++q2) {
        int flat = q2 * 64 + lane;
        int row = flat >> 3, part = flat & 7;
        uint4 val = *(uint4*)&myvs[row * 72 + part * 8];
        *(uint4*)&vtb[row * 2048 + tbase + part * 8] = val;
      }
    }
  } else {  // MODE 1: fp32 store
#pragma unroll
    for (int tm = 0; tm < 4; tm++) {
#pragma unroll
      for (int reg = 0; reg < 4; reg++) {
        int m = m0 + wm * 64 + tm * 16 + quad * 4 + reg;
#pragma unroll
        for (int tn = 0; tn < 4; tn++)
          fo[m * 1024 + nbase + tn * 16 + r] = acc[tm][tn][reg];
      }
    }
  }
}

// ---------------- flash attention, sliding window, GQA ----------------
// Computes S^T = K*Q^T so softmax's key-reduction is in-lane; PV as O^T = Vt*P^T.
// grid (32 qblocks, 16 heads, 2 batch), 256 threads (4 waves x 16 queries).

__global__ __launch_bounds__(256) void attn_kernel(
    const u16* __restrict__ Q, const u16* __restrict__ K,
    const u16* __restrict__ Vt, u16* __restrict__ O) {
  __shared__ u16 k_s[64 * 64];   // [key j][dim d]
  __shared__ u16 v_s[64 * 64];   // [dim d][key j]   (from global Vt)
  __shared__ u16 pt[4 * 16 * 72];  // per-wave [query i][key j] bf16
  int tid = threadIdx.x, w = tid >> 6, lane = tid & 63, quad = lane >> 4, r = lane & 15;
  int qb = blockIdx.x, h = blockIdx.y, b = blockIdx.z;
  int i0 = qb * 64;
  int hk = h >> 2;
  int qw0 = i0 + w * 16;  // wave's first query
  int iq = qw0 + r;       // this lane's query

  // Q as B-operand: lane r <-> query col, contiguous dims (Q pre-scaled by 1/8)
  const u16* qptr = Q + (size_t)((b * N_H + h) * N_L + iq) * HDIM;
  short8 qf[2];
  qf[0] = *(const short8*)&qptr[quad * 8];
  qf[1] = *(const short8*)&qptr[32 + quad * 8];

  const u16* kbase = K + (size_t)(b * N_KVH + hk) * N_L * HDIM;
  const u16* vtbase = Vt + (size_t)(b * N_KVH + hk) * HDIM * N_L;

  f32x4 zero4 = {0.f, 0.f, 0.f, 0.f};
  float m_r = -1e30f, l_r = 0.f;
  f32x4 o_acc[4];
#pragma unroll
  for (int tm = 0; tm < 4; tm++) o_acc[tm] = zero4;

  int jt0 = (i0 >= WINDOW) ? ((i0 - (WINDOW - 1)) >> 6) : 0;
  u16* mypt = pt + w * 1152;

  for (int jt = jt0; jt <= qb; ++jt) {
    int j0 = jt << 6;
    // async stage K [j][d] and Vt [d][j], 16B/lane, lane-ordered LDS dests
#pragma unroll
    for (int it = 0; it < 2; ++it) {
      int cc = it * 256 + tid;
      int row = cc >> 3, part = cc & 7;
      gl2lds16(&kbase[(j0 + row) * 64 + part * 8], &k_s[cc * 8]);
    }
#pragma unroll
    for (int it = 0; it < 2; ++it) {
      int cc = it * 256 + tid;
      int row = cc >> 3, part = cc & 7;
      gl2lds16(&vtbase[row * 2048 + j0 + part * 8], &v_s[cc * 8]);
    }
    __syncthreads();

    // S^T[j][i]: A = K rows (j), B = Q rows (i)
    f32x4 s_acc[4];
#pragma unroll
    for (int tm = 0; tm < 4; tm++) s_acc[tm] = zero4;
#pragma unroll
    for (int ks = 0; ks < 2; ks++) {
#pragma unroll
      for (int tm = 0; tm < 4; tm++) {
        short8 kf = *(const short8*)&k_s[(tm * 16 + r) * 64 + ks * 32 + quad * 8];
        s_acc[tm] = __builtin_amdgcn_mfma_f32_16x16x32_bf16(kf, qf[ks], s_acc[tm], 0, 0, 0);
      }
    }

    // mask only on edge tiles (wave-uniform branch)
    float sv[4][4];
#pragma unroll
    for (int tm = 0; tm < 4; tm++)
#pragma unroll
      for (int reg = 0; reg < 4; reg++) sv[tm][reg] = s_acc[tm][reg];
    bool need_mask = !((j0 + 63 <= qw0) && (qw0 + 15 - j0 < WINDOW));
    if (need_mask) {
#pragma unroll
      for (int tm = 0; tm < 4; tm++) {
#pragma unroll
        for (int reg = 0; reg < 4; reg++) {
          int j = j0 + tm * 16 + quad * 4 + reg;
          bool ok = (j <= iq) && (iq - j < WINDOW);
          if (!ok) sv[tm][reg] = -3.0e37f;
        }
      }
    }

    // online softmax: all 16 values in-lane; combine across quads with 2 shfl
    float tmax = sv[0][0];
#pragma unroll
    for (int tm = 0; tm < 4; tm++)
#pragma unroll
      for (int reg = 0; reg < 4; reg++) tmax = fmaxf(tmax, sv[tm][reg]);
    tmax = fmaxf(tmax, __shfl_xor(tmax, 16));
    tmax = fmaxf(tmax, __shfl_xor(tmax, 32));
    float mnew = fmaxf(m_r, tmax);
    float alpha = __expf(m_r - mnew);
    m_r = mnew;
    float p[4][4], rsum = 0.f;
#pragma unroll
    for (int tm = 0; tm < 4; tm++)
#pragma unroll
      for (int reg = 0; reg < 4; reg++) {
        float e = __expf(sv[tm][reg] - mnew);
        p[tm][reg] = e;
        rsum += e;
      }
    rsum += __shfl_xor(rsum, 16);
    rsum += __shfl_xor(rsum, 32);
    l_r = l_r * alpha + rsum;
#pragma unroll
    for (int tm = 0; tm < 4; tm++)
#pragma unroll
      for (int reg = 0; reg < 4; reg++) o_acc[tm][reg] *= alpha;

    // P^T (C-layout) -> pt[i][j] (wave-local, conflict-free)
#pragma unroll
    for (int tm = 0; tm < 4; tm++) {
      U2 pk;
#pragma unroll
      for (int reg = 0; reg < 4; reg++) pk.h[reg] = f2bf(p[tm][reg]);
      *(uint2*)&mypt[r * 72 + tm * 16 + quad * 4] = pk.v;
    }
    __asm__ volatile("s_waitcnt lgkmcnt(0)" ::: "memory");  // wave-local LDS RAW

    // O^T += Vt * P^T : A = Vt rows (d), B = pt rows (i)
#pragma unroll
    for (int ks = 0; ks < 2; ks++) {
      short8 bp = *(const short8*)&mypt[r * 72 + ks * 32 + quad * 8];
#pragma unroll
      for (int tm = 0; tm < 4; tm++) {
        short8 av = *(const short8*)&v_s[(tm * 16 + r) * 64 + ks * 32 + quad * 8];
        o_acc[tm] = __builtin_amdgcn_mfma_f32_16x16x32_bf16(av, bp, o_acc[tm], 0, 0, 0);
      }
    }
    __syncthreads();
  }

  // epilogue: O^T lane holds (d = tm*16+quad*4+reg, i = r); /l, pack 4 d's
  float inv = 1.0f / l_r;
  size_t obase = (size_t)(b * N_L + iq) * 1024 + h * 64;
#pragma unroll
  for (int tm = 0; tm < 4; tm++) {
    U2 pk;
#pragma unroll
    for (int reg = 0; reg < 4; reg++) pk.h[reg] = f2bf(o_acc[tm][reg] * inv);
    *(uint2*)&O[obase + tm * 16 + quad * 4] = pk.v;
  }
}

// ---------------- launch ----------------

extern "C" void kernel_launch(void* const* d_in, const int* in_sizes, int n_in,
                              void* d_out, int out_size, void* d_ws, size_t ws_size,
                              hipStream_t stream) {
  const float* x = (const float*)d_in[0];
  const float* Wq = (const float*)d_in[1];
  const float* Wk = (const float*)d_in[2];
  const float* Wv = (const float*)d_in[3];
  const float* Wo = (const float*)d_in[4];
  float* out = (float*)d_out;
  char* ws = (char*)d_ws;

  u16* xb    = (u16*)(ws);                // 8 MB  [4096][1024]
  u16* wqkvT = (u16*)(ws + 0x800000);     // 3 MB  [1536][1024]
  u16* woT   = (u16*)(ws + 0xB00000);     // 2 MB  [1024][1024]
  u16* Qb    = (u16*)(ws + 0xD00000);     // 8 MB  [B][H][L][64] (pre-scaled 1/8)
  u16* Kb    = (u16*)(ws + 0x1500000);    // 2 MB  [B][KvH][L][64]
  u16* Vtb   = (u16*)(ws + 0x1700000);    // 2 MB  [B][KvH][64][L]  (transposed!)
  u16* Ob    = (u16*)(ws + 0x1900000);    // 8 MB  [4096][1024]
  float* rc  = (float*)(ws + 0x2100000);  // 256 KB [2048][32]
  float* rs  = (float*)(ws + 0x2140000);  // 256 KB

  convert_x<<<4096, 256, 0, stream>>>(x, xb);
  dim3 tb(32, 8);
  transpose_w<<<dim3(32, 32), tb, 0, stream>>>(Wq, wqkvT, 1024);
  transpose_w<<<dim3(8, 32), tb, 0, stream>>>(Wk, wqkvT + 1024 * 1024, 256);
  transpose_w<<<dim3(8, 32), tb, 0, stream>>>(Wv, wqkvT + 1280 * 1024, 256);
  transpose_w<<<dim3(32, 32), tb, 0, stream>>>(Wo, woT, 1024);
  rope_table<<<256, 256, 0, stream>>>(rc, rs);

  gemm_kernel<0><<<dim3(12, 32), 256, 0, stream>>>(xb, wqkvT, Qb, Kb, Vtb, nullptr, rc, rs);
  attn_kernel<<<dim3(32, 16, 2), 256, 0, stream>>>(Qb, Kb, Vtb, Ob);
  gemm_kernel<1><<<dim3(8, 32), 256, 0, stream>>>(Ob, woT, nullptr, nullptr, nullptr, out, nullptr, nullptr);
}

// Round 3
// 170.604 us; speedup vs baseline: 1.4465x; 1.1495x over previous
//
#include <hip/hip_runtime.h>

typedef unsigned short u16;
typedef unsigned int u32;
typedef short short8 __attribute__((ext_vector_type(8)));
typedef float f32x4 __attribute__((ext_vector_type(4)));

#define N_B 2
#define N_L 2048
#define N_D 1024
#define N_H 16
#define N_KVH 4
#define HDIM 64
#define WINDOW 1024

// log2(e) folded into Q so softmax can use exp2 directly
#define QSCALE (0.125f * 1.44269504088896f)

__device__ __forceinline__ u16 f2bf(float f) {
  unsigned u = __builtin_bit_cast(unsigned, f);
  u = u + 0x7fffu + ((u >> 16) & 1u);
  return (u16)(u >> 16);
}

// pack two f32 -> (bf16(hi)<<16)|bf16(lo), round-half-up, one v_perm
__device__ __forceinline__ u32 pk2bf(float lo, float hi) {
  u32 a = __builtin_bit_cast(u32, lo) + 0x8000u;
  u32 b = __builtin_bit_cast(u32, hi) + 0x8000u;
  return __builtin_amdgcn_perm(b, a, 0x07060302u);
}

union U2 {
  u16 h[4];
  uint2 v;
};

// async global->LDS, 16B per lane. LDS dest must be wave-uniform base + lane*16.
__device__ __forceinline__ void gl2lds16(const u16* g, u16* l) {
  __builtin_amdgcn_global_load_lds((const __attribute__((address_space(1))) void*)g,
                                   (__attribute__((address_space(3))) void*)l, 16, 0, 0);
}

// ---------------- fused prep: convert x, transpose 4 weights, rope ----------------

__global__ __launch_bounds__(256) void prep_kernel(
    const float* __restrict__ x, const float* __restrict__ Wq, const float* __restrict__ Wk,
    const float* __restrict__ Wv, const float* __restrict__ Wo,
    u16* __restrict__ xb, u16* __restrict__ wqkvT, u16* __restrict__ woT,
    float* __restrict__ rc, float* __restrict__ rs) {
  __shared__ float tbuf[32][33];
  int bid = blockIdx.x, tid = threadIdx.x;
  if (bid < 1024) {  // x fp32 -> bf16, 16 elems/thread
    size_t base = ((size_t)bid * 256 + tid) * 16;
    u32 o[8];
#pragma unroll
    for (int j = 0; j < 4; j++) {
      float4 f = *(const float4*)&x[base + j * 4];
      o[2 * j] = pk2bf(f.x, f.y);
      o[2 * j + 1] = pk2bf(f.z, f.w);
    }
    *(uint4*)&xb[base] = *(uint4*)&o[0];
    *(uint4*)&xb[base + 8] = *(uint4*)&o[4];
  } else if (bid < 3584) {  // weight transposes [1024][srcN] -> [srcN][1024] bf16
    const float* src;
    u16* dst;
    int gx, t, shift;
    if (bid < 2048) { src = Wq; dst = wqkvT; gx = 32; shift = 5; t = bid - 1024; }
    else if (bid < 2304) { src = Wk; dst = wqkvT + 1024 * 1024; gx = 8; shift = 3; t = bid - 2048; }
    else if (bid < 2560) { src = Wv; dst = wqkvT + 1280 * 1024; gx = 8; shift = 3; t = bid - 2304; }
    else { src = Wo; dst = woT; gx = 32; shift = 5; t = bid - 2560; }
    int srcN = gx * 32;
    int n0 = (t & (gx - 1)) * 32, k0 = (t >> shift) * 32;
    int lx = tid & 31, ly = tid >> 5;
#pragma unroll
    for (int q = 0; q < 4; q++)
      tbuf[ly + 8 * q][lx] = src[(k0 + ly + 8 * q) * srcN + n0 + lx];
    __syncthreads();
#pragma unroll
    for (int q = 0; q < 4; q++)
      dst[(n0 + ly + 8 * q) * 1024 + k0 + lx] = f2bf(tbuf[lx][ly + 8 * q]);
  } else {  // rope tables, 2048*32
    int idx = (bid - 3584) * 256 + tid;
    int i = idx >> 5, j = idx & 31;
    float inv = powf(10000.0f, -(float)j * (1.0f / 32.0f));
    float ang = (float)i * inv;
    rc[idx] = cosf(ang);
    rs[idx] = sinf(ang);
  }
}

// ---------------- GEMM: C[M,N] = A[M,K=1024] * Bt[N,K=1024]^T ----------------
// MODE 0: qkv projection; RoPE epilogue (Q scaled by QSCALE); V stored transposed
//         globally as Vt[b][hkv][64][2048].
// MODE 1: out projection, fp32 store.

template <int MODE>
__global__ __launch_bounds__(256) void gemm_kernel(
    const u16* __restrict__ A, const u16* __restrict__ Bt,
    u16* __restrict__ qo, u16* __restrict__ ko, u16* __restrict__ vo,
    float* __restrict__ fo, const float* __restrict__ rc, const float* __restrict__ rs) {
  __shared__ u16 a_s[128 * 32];
  __shared__ u16 b_s[128 * 32];
  int tid = threadIdx.x;
  int w = tid >> 6, lane = tid & 63, quad = lane >> 4, r = lane & 15;
  int wm = w >> 1, wn = w & 1;
  int m0 = blockIdx.y * 128, n0 = blockIdx.x * 128;

  f32x4 zero4 = {0.f, 0.f, 0.f, 0.f};
  f32x4 acc[4][4];
#pragma unroll
  for (int a_ = 0; a_ < 4; a_++)
#pragma unroll
    for (int b_ = 0; b_ < 4; b_++) acc[a_][b_] = zero4;

  for (int kt = 0; kt < 32; ++kt) {
#pragma unroll
    for (int it = 0; it < 2; ++it) {
      int cc = it * 256 + tid;
      int row = cc >> 2, part = cc & 3;  // 32 elems/row = 4 chunks of 8
      gl2lds16(&A[(m0 + row) * 1024 + kt * 32 + part * 8], &a_s[cc * 8]);
      gl2lds16(&Bt[(n0 + row) * 1024 + kt * 32 + part * 8], &b_s[cc * 8]);
    }
    __syncthreads();
    short8 af[4], bfr[4];
#pragma unroll
    for (int tm = 0; tm < 4; tm++)
      af[tm] = *(const short8*)&a_s[(wm * 64 + tm * 16 + r) * 32 + quad * 8];
#pragma unroll
    for (int tn = 0; tn < 4; tn++)
      bfr[tn] = *(const short8*)&b_s[(wn * 64 + tn * 16 + r) * 32 + quad * 8];
#pragma unroll
    for (int tm = 0; tm < 4; tm++)
#pragma unroll
      for (int tn = 0; tn < 4; tn++)
        acc[tm][tn] = __builtin_amdgcn_mfma_f32_16x16x32_bf16(af[tm], bfr[tn], acc[tm][tn], 0, 0, 0);
    __syncthreads();
  }

  int nbase = n0 + wn * 64;  // 64-aligned, uniform per wave
  if constexpr (MODE == 0) {
    if (nbase < 1024) {  // Q + RoPE + QSCALE
      int h = nbase >> 6;
#pragma unroll
      for (int tm = 0; tm < 4; tm++) {
#pragma unroll
        for (int reg = 0; reg < 4; reg++) {
          int m = m0 + wm * 64 + tm * 16 + quad * 4 + reg;
          int b = m >> 11, i = m & 2047;
          int base = ((b * N_H + h) * N_L + i) * HDIM;
#pragma unroll
          for (int tn = 0; tn < 2; tn++) {
            int dlo = tn * 16 + r;
            float c = rc[i * 32 + dlo], s = rs[i * 32 + dlo];
            float vlo = acc[tm][tn][reg], vhi = acc[tm][tn + 2][reg];
            qo[base + dlo] = f2bf((vlo * c - vhi * s) * QSCALE);
            qo[base + dlo + 32] = f2bf((vhi * c + vlo * s) * QSCALE);
          }
        }
      }
    } else if (nbase < 1280) {  // K + RoPE
      int h = (nbase - 1024) >> 6;
#pragma unroll
      for (int tm = 0; tm < 4; tm++) {
#pragma unroll
        for (int reg = 0; reg < 4; reg++) {
          int m = m0 + wm * 64 + tm * 16 + quad * 4 + reg;
          int b = m >> 11, i = m & 2047;
          int base = ((b * N_KVH + h) * N_L + i) * HDIM;
#pragma unroll
          for (int tn = 0; tn < 2; tn++) {
            int dlo = tn * 16 + r;
            float c = rc[i * 32 + dlo], s = rs[i * 32 + dlo];
            float vlo = acc[tm][tn][reg], vhi = acc[tm][tn + 2][reg];
            ko[base + dlo] = f2bf(vlo * c - vhi * s);
            ko[base + dlo + 32] = f2bf(vhi * c + vlo * s);
          }
        }
      }
    } else {  // V: transpose via LDS bounce -> Vt[b][hkv][64][2048]
      __shared__ u16 vs[4 * 64 * 72];
      int hkv = (nbase - 1280) >> 6;
      int bb = (m0 + wm * 64) >> 11;
      int tbase = (m0 + wm * 64) & 2047;
      u16* myvs = vs + w * 4608;
#pragma unroll
      for (int tm = 0; tm < 4; tm++) {
#pragma unroll
        for (int tn = 0; tn < 4; tn++) {
          U2 pk;
          pk.v.x = pk2bf(acc[tm][tn][0], acc[tm][tn][1]);
          pk.v.y = pk2bf(acc[tm][tn][2], acc[tm][tn][3]);
          *(uint2*)&myvs[(tn * 16 + r) * 72 + tm * 16 + quad * 4] = pk.v;
        }
      }
      __asm__ volatile("s_waitcnt lgkmcnt(0)" ::: "memory");  // wave-local LDS RAW
      u16* vtb = vo + (size_t)((bb * N_KVH + hkv) * 64) * 2048;
#pragma unroll
      for (int q2 = 0; q2 < 8; ++q2) {
        int flat = q2 * 64 + lane;
        int row = flat >> 3, part = flat & 7;
        uint4 val = *(uint4*)&myvs[row * 72 + part * 8];
        *(uint4*)&vtb[row * 2048 + tbase + part * 8] = val;
      }
    }
  } else {  // MODE 1: fp32 store
#pragma unroll
    for (int tm = 0; tm < 4; tm++) {
#pragma unroll
      for (int reg = 0; reg < 4; reg++) {
        int m = m0 + wm * 64 + tm * 16 + quad * 4 + reg;
#pragma unroll
        for (int tn = 0; tn < 4; tn++)
          fo[m * 1024 + nbase + tn * 16 + r] = acc[tm][tn][reg];
      }
    }
  }
}

// ---------------- flash attention, sliding window, GQA ----------------
// S^T = K*Q^T (key-reduction in-lane), O^T = Vt*P^T.
// XOR-swizzled LDS (chunk p = c ^ (row&7)) -> b128 reads at the 8-cycle floor.
// Double-buffered K/V staging, ONE barrier per tile.
// grid (32 qblocks, 16 heads, 2 batch), 256 threads (4 waves x 16 queries).

__global__ __launch_bounds__(256) void attn_kernel(
    const u16* __restrict__ Q, const u16* __restrict__ K,
    const u16* __restrict__ Vt, u16* __restrict__ O) {
  __shared__ u16 k_s[2][64 * 64];
  __shared__ u16 v_s[2][64 * 64];
  __shared__ u16 pt[4][16 * 64];
  int tid = threadIdx.x, w = tid >> 6, lane = tid & 63, quad = lane >> 4, r = lane & 15;
  int qb = blockIdx.x, h = blockIdx.y, b = blockIdx.z;
  int i0 = qb * 64;
  int hk = h >> 2;
  int qw0 = i0 + w * 16;
  int iq = qw0 + r;

  const u16* qptr = Q + (size_t)((b * N_H + h) * N_L + iq) * HDIM;
  short8 qf[2];
  qf[0] = *(const short8*)&qptr[quad * 8];
  qf[1] = *(const short8*)&qptr[32 + quad * 8];

  const u16* kbase = K + (size_t)(b * N_KVH + hk) * N_L * HDIM;
  const u16* vtbase = Vt + (size_t)(b * N_KVH + hk) * HDIM * N_L;

  // stage tile jt into buffer buf (async; swizzled source permutation)
  auto stage = [&](int jt, int buf) {
#pragma unroll
    for (int it = 0; it < 2; ++it) {
      int cc = it * 256 + tid;
      int row = cc >> 3, p = cc & 7, c = p ^ (row & 7);
      gl2lds16(&kbase[(size_t)(jt * 64 + row) * 64 + c * 8], &k_s[buf][cc * 8]);
    }
#pragma unroll
    for (int it = 0; it < 2; ++it) {
      int cc = it * 256 + tid;
      int row = cc >> 3, p = cc & 7, c = p ^ (row & 7);
      gl2lds16(&vtbase[(size_t)row * 2048 + jt * 64 + c * 8], &v_s[buf][cc * 8]);
    }
  };

  f32x4 zero4 = {0.f, 0.f, 0.f, 0.f};
  float m_r = -1e30f, l_r = 0.f;
  f32x4 o_acc[4];
#pragma unroll
  for (int tm = 0; tm < 4; tm++) o_acc[tm] = zero4;

  int jt0 = (i0 >= WINDOW) ? ((i0 - (WINDOW - 1)) >> 6) : 0;
  int nt = qb - jt0 + 1;
  u16* mypt = pt[w];
  int rx = r & 7;

  stage(jt0, 0);

  for (int t = 0; t < nt; ++t) {
    int jt = jt0 + t, j0 = jt << 6, buf = t & 1;
    __syncthreads();  // drains vmcnt: buf's staging complete
    if (t + 1 < nt) stage(jt + 1, buf ^ 1);

    // S^T[j][i]: A = K rows (j), B = Q (i)
    f32x4 s_acc[4];
#pragma unroll
    for (int tm = 0; tm < 4; tm++) s_acc[tm] = zero4;
#pragma unroll
    for (int ks = 0; ks < 2; ks++) {
#pragma unroll
      for (int tm = 0; tm < 4; tm++) {
        int pc = (ks * 4 + quad) ^ rx;
        short8 kf = *(const short8*)&k_s[buf][(tm * 16 + r) * 64 + pc * 8];
        s_acc[tm] = __builtin_amdgcn_mfma_f32_16x16x32_bf16(kf, qf[ks], s_acc[tm], 0, 0, 0);
      }
    }

    bool interior = (j0 + 63 <= qw0) && (qw0 + 15 - j0 < WINDOW);
    if (!interior) {
#pragma unroll
      for (int tm = 0; tm < 4; tm++) {
#pragma unroll
        for (int reg = 0; reg < 4; reg++) {
          int j = j0 + tm * 16 + quad * 4 + reg;
          bool ok = (j <= iq) && (iq - j < WINDOW);
          if (!ok) s_acc[tm][reg] = -1e30f;
        }
      }
    }

    // online softmax (log2 domain): 16 scores in-lane, quad-combine via 2 shfl
    float tmax = s_acc[0][0];
#pragma unroll
    for (int tm = 0; tm < 4; tm++)
#pragma unroll
      for (int reg = 0; reg < 4; reg++) tmax = fmaxf(tmax, s_acc[tm][reg]);
    tmax = fmaxf(tmax, __shfl_xor(tmax, 16));
    tmax = fmaxf(tmax, __shfl_xor(tmax, 32));
    float mnew = fmaxf(m_r, tmax);
    float alpha = __builtin_amdgcn_exp2f(m_r - mnew);
    m_r = mnew;
    float p[4][4], rsum = 0.f;
#pragma unroll
    for (int tm = 0; tm < 4; tm++)
#pragma unroll
      for (int reg = 0; reg < 4; reg++) {
        float e = __builtin_amdgcn_exp2f(s_acc[tm][reg] - mnew);
        p[tm][reg] = e;
        rsum += e;
      }
    rsum += __shfl_xor(rsum, 16);
    rsum += __shfl_xor(rsum, 32);
    l_r = l_r * alpha + rsum;
#pragma unroll
    for (int tm = 0; tm < 4; tm++) o_acc[tm] *= alpha;

    // P^T (C-layout) -> pt[i][j] swizzled, wave-local
#pragma unroll
    for (int tm = 0; tm < 4; tm++) {
      uint2 pk;
      pk.x = pk2bf(p[tm][0], p[tm][1]);
      pk.y = pk2bf(p[tm][2], p[tm][3]);
      int c = tm * 2 + (quad >> 1), half = quad & 1;
      int pp = c ^ rx;
      *(uint2*)&mypt[r * 64 + pp * 8 + half * 4] = pk;
    }
    __asm__ volatile("s_waitcnt lgkmcnt(0)" ::: "memory");  // wave-local LDS RAW

    // O^T += Vt * P^T : A = Vt rows (d), B = pt rows (i)
#pragma unroll
    for (int ks = 0; ks < 2; ks++) {
      int pc = (ks * 4 + quad) ^ rx;
      short8 bp = *(const short8*)&mypt[r * 64 + pc * 8];
#pragma unroll
      for (int tm = 0; tm < 4; tm++) {
        short8 av = *(const short8*)&v_s[buf][(tm * 16 + r) * 64 + pc * 8];
        o_acc[tm] = __builtin_amdgcn_mfma_f32_16x16x32_bf16(av, bp, o_acc[tm], 0, 0, 0);
      }
    }
  }

  // epilogue: lane holds (d = tm*16+quad*4+reg, query iq); /l, pack pairs
  float inv = 1.0f / l_r;
  size_t obase = (size_t)(b * N_L + iq) * 1024 + h * 64;
#pragma unroll
  for (int tm = 0; tm < 4; tm++) {
    uint2 pk;
    pk.x = pk2bf(o_acc[tm][0] * inv, o_acc[tm][1] * inv);
    pk.y = pk2bf(o_acc[tm][2] * inv, o_acc[tm][3] * inv);
    *(uint2*)&O[obase + tm * 16 + quad * 4] = pk;
  }
}

// ---------------- launch ----------------

extern "C" void kernel_launch(void* const* d_in, const int* in_sizes, int n_in,
                              void* d_out, int out_size, void* d_ws, size_t ws_size,
                              hipStream_t stream) {
  const float* x = (const float*)d_in[0];
  const float* Wq = (const float*)d_in[1];
  const float* Wk = (const float*)d_in[2];
  const float* Wv = (const float*)d_in[3];
  const float* Wo = (const float*)d_in[4];
  float* out = (float*)d_out;
  char* ws = (char*)d_ws;

  u16* xb    = (u16*)(ws);                // 8 MB  [4096][1024]
  u16* wqkvT = (u16*)(ws + 0x800000);     // 3 MB  [1536][1024]
  u16* woT   = (u16*)(ws + 0xB00000);     // 2 MB  [1024][1024]
  u16* Qb    = (u16*)(ws + 0xD00000);     // 8 MB  [B][H][L][64] (pre-scaled QSCALE)
  u16* Kb    = (u16*)(ws + 0x1500000);    // 2 MB  [B][KvH][L][64]
  u16* Vtb   = (u16*)(ws + 0x1700000);    // 2 MB  [B][KvH][64][L]  (transposed)
  u16* Ob    = (u16*)(ws + 0x1900000);    // 8 MB  [4096][1024]
  float* rc  = (float*)(ws + 0x2100000);  // 256 KB [2048][32]
  float* rs  = (float*)(ws + 0x2140000);  // 256 KB

  prep_kernel<<<3840, 256, 0, stream>>>(x, Wq, Wk, Wv, Wo, xb, wqkvT, woT, rc, rs);
  gemm_kernel<0><<<dim3(12, 32), 256, 0, stream>>>(xb, wqkvT, Qb, Kb, Vtb, nullptr, rc, rs);
  attn_kernel<<<dim3(32, 16, 2), 256, 0, stream>>>(Qb, Kb, Vtb, Ob);
  gemm_kernel<1><<<dim3(8, 32), 256, 0, stream>>>(Ob, woT, nullptr, nullptr, nullptr, out, nullptr, nullptr);
}

// Round 4
// 155.420 us; speedup vs baseline: 1.5878x; 1.0977x over previous
//
#include <hip/hip_runtime.h>

typedef unsigned short u16;
typedef unsigned int u32;
typedef short short8 __attribute__((ext_vector_type(8)));
typedef float f32x4 __attribute__((ext_vector_type(4)));

#define N_B 2
#define N_L 2048
#define N_D 1024
#define N_H 16
#define N_KVH 4
#define HDIM 64
#define WINDOW 1024

// log2(e) folded into Q so softmax can use exp2 directly
#define QSCALE (0.125f * 1.44269504088896f)

__device__ __forceinline__ u16 f2bf(float f) {
  unsigned u = __builtin_bit_cast(unsigned, f);
  u = u + 0x7fffu + ((u >> 16) & 1u);
  return (u16)(u >> 16);
}

// pack two f32 -> (bf16(hi)<<16)|bf16(lo), round-half-up, one v_perm
__device__ __forceinline__ u32 pk2bf(float lo, float hi) {
  u32 a = __builtin_bit_cast(u32, lo) + 0x8000u;
  u32 b = __builtin_bit_cast(u32, hi) + 0x8000u;
  return __builtin_amdgcn_perm(b, a, 0x07060302u);
}

// async global->LDS, 16B per lane. LDS dest must be wave-uniform base + lane*16.
__device__ __forceinline__ void gl2lds16(const u16* g, u16* l) {
  __builtin_amdgcn_global_load_lds((const __attribute__((address_space(1))) void*)g,
                                   (__attribute__((address_space(3))) void*)l, 16, 0, 0);
}

// ---------------- fused prep: convert x, transpose 4 weights, rope ----------------

__global__ __launch_bounds__(256) void prep_kernel(
    const float* __restrict__ x, const float* __restrict__ Wq, const float* __restrict__ Wk,
    const float* __restrict__ Wv, const float* __restrict__ Wo,
    u16* __restrict__ xb, u16* __restrict__ wqkvT, u16* __restrict__ woT,
    float* __restrict__ rc, float* __restrict__ rs) {
  __shared__ float tbuf[32][33];
  int bid = blockIdx.x, tid = threadIdx.x;
  if (bid < 1024) {  // x fp32 -> bf16, 16 elems/thread
    size_t base = ((size_t)bid * 256 + tid) * 16;
    u32 o[8];
#pragma unroll
    for (int j = 0; j < 4; j++) {
      float4 f = *(const float4*)&x[base + j * 4];
      o[2 * j] = pk2bf(f.x, f.y);
      o[2 * j + 1] = pk2bf(f.z, f.w);
    }
    *(uint4*)&xb[base] = *(uint4*)&o[0];
    *(uint4*)&xb[base + 8] = *(uint4*)&o[4];
  } else if (bid < 3584) {  // weight transposes [1024][srcN] -> [srcN][1024] bf16
    const float* src;
    u16* dst;
    int gx, t, shift;
    if (bid < 2048) { src = Wq; dst = wqkvT; gx = 32; shift = 5; t = bid - 1024; }
    else if (bid < 2304) { src = Wk; dst = wqkvT + 1024 * 1024; gx = 8; shift = 3; t = bid - 2048; }
    else if (bid < 2560) { src = Wv; dst = wqkvT + 1280 * 1024; gx = 8; shift = 3; t = bid - 2304; }
    else { src = Wo; dst = woT; gx = 32; shift = 5; t = bid - 2560; }
    int srcN = gx * 32;
    int n0 = (t & (gx - 1)) * 32, k0 = (t >> shift) * 32;
    int lx = tid & 31, ly = tid >> 5;
#pragma unroll
    for (int q = 0; q < 4; q++)
      tbuf[ly + 8 * q][lx] = src[(k0 + ly + 8 * q) * srcN + n0 + lx];
    __syncthreads();
#pragma unroll
    for (int q = 0; q < 4; q++)
      dst[(n0 + ly + 8 * q) * 1024 + k0 + lx] = f2bf(tbuf[lx][ly + 8 * q]);
  } else {  // rope tables, 2048*32
    int idx = (bid - 3584) * 256 + tid;
    int i = idx >> 5, j = idx & 31;
    float inv = powf(10000.0f, -(float)j * (1.0f / 32.0f));
    float ang = (float)i * inv;
    rc[idx] = cosf(ang);
    rs[idx] = sinf(ang);
  }
}

// ---------------- GEMM: C[M,N] = A[M,K=1024] * Bt[N,K=1024]^T ----------------
// 64(M) x 128(N) tile, BK=64, 4 waves (each 16 rows x 128 cols), XOR-swizzled LDS.
// MODE 0: qkv projection; RoPE epilogue (Q scaled by QSCALE); V stored transposed
//         globally as Vt[b][hkv][64][2048].  Grid (12, 64).
// MODE 1: out projection, fp32 store. Grid (8, 64).

template <int MODE>
__global__ __launch_bounds__(256) void gemm_kernel(
    const u16* __restrict__ A, const u16* __restrict__ Bt,
    u16* __restrict__ qo, u16* __restrict__ ko, u16* __restrict__ vo,
    float* __restrict__ fo, const float* __restrict__ rc, const float* __restrict__ rs) {
  __shared__ u16 smem[64 * 64 + 128 * 64];  // 24576 B
  u16* a_s = smem;             // [64 m][64 k] swizzled
  u16* b_s = smem + 64 * 64;   // [128 n][64 k] swizzled
  int tid = threadIdx.x;
  int w = tid >> 6, lane = tid & 63, quad = lane >> 4, r = lane & 15;
  int rx = r & 7;
  int m0 = blockIdx.y * 64, n0 = blockIdx.x * 128;

  f32x4 acc[8];
#pragma unroll
  for (int t = 0; t < 8; t++) acc[t] = {0.f, 0.f, 0.f, 0.f};

  for (int kt = 0; kt < 16; ++kt) {
#pragma unroll
    for (int it = 0; it < 2; ++it) {  // A: 64 rows x 8 chunks
      int cc = it * 256 + tid;
      int row = cc >> 3, p = cc & 7, c = p ^ (row & 7);
      gl2lds16(&A[(size_t)(m0 + row) * 1024 + kt * 64 + c * 8], &a_s[cc * 8]);
    }
#pragma unroll
    for (int it = 0; it < 4; ++it) {  // B: 128 rows x 8 chunks
      int cc = it * 256 + tid;
      int row = cc >> 3, p = cc & 7, c = p ^ (row & 7);
      gl2lds16(&Bt[(size_t)(n0 + row) * 1024 + kt * 64 + c * 8], &b_s[cc * 8]);
    }
    __syncthreads();
#pragma unroll
    for (int ks = 0; ks < 2; ks++) {
      int pc = (ks * 4 + quad) ^ rx;
      short8 af = *(const short8*)&a_s[(w * 16 + r) * 64 + pc * 8];
#pragma unroll
      for (int tn = 0; tn < 8; tn++) {
        short8 bf = *(const short8*)&b_s[(tn * 16 + r) * 64 + pc * 8];
        acc[tn] = __builtin_amdgcn_mfma_f32_16x16x32_bf16(af, bf, acc[tn], 0, 0, 0);
      }
    }
    __syncthreads();
  }

  // lane owns C elements (m = m0 + w*16 + quad*4 + reg, n = n0 + tn*16 + r)
  if constexpr (MODE == 0) {
    if (n0 < 1280) {  // Q or K with RoPE
      bool isQ = (n0 < 1024);
#pragma unroll
      for (int tg = 0; tg < 2; tg++) {      // pairs: tlo in {0,1,4,5}, thi = tlo+2
#pragma unroll
        for (int tp = 0; tp < 2; tp++) {
          int tlo = tg * 4 + tp;
          int nlo = n0 + tlo * 16 + r;
          int dlo = (tlo * 16 + r) & 63;    // in [0,32)
          int h = isQ ? (nlo >> 6) : ((nlo - 1024) >> 6);
          int nh = isQ ? N_H : N_KVH;
          u16* dstp = isQ ? qo : ko;
          float sc = isQ ? QSCALE : 1.0f;
#pragma unroll
          for (int reg = 0; reg < 4; reg++) {
            int m = m0 + w * 16 + quad * 4 + reg;
            int bb = m >> 11, i = m & 2047;
            float c = rc[i * 32 + dlo], s = rs[i * 32 + dlo];
            float vlo = acc[tlo][reg], vhi = acc[tlo + 2][reg];
            size_t base = ((size_t)(bb * nh + h) * N_L + i) * HDIM;
            dstp[base + dlo] = f2bf((vlo * c - vhi * s) * sc);
            dstp[base + dlo + 32] = f2bf((vhi * c + vlo * s) * sc);
          }
        }
      }
    } else {  // V: transpose bounce through reused smem -> Vt[b][hkv][64][2048]
      int v0 = n0 - 1280;                     // 0 or 128
      int token0 = (m0 + w * 16) & 2047;
      int bb = m0 >> 11;
      u16* myvs = smem + w * (128 * 24);      // [128 d][16 tok] stride 24, 6144 B/wave
#pragma unroll
      for (int tn = 0; tn < 8; tn++) {
        uint2 pk;
        pk.x = pk2bf(acc[tn][0], acc[tn][1]);
        pk.y = pk2bf(acc[tn][2], acc[tn][3]);
        *(uint2*)&myvs[(tn * 16 + r) * 24 + quad * 4] = pk;
      }
      __asm__ volatile("s_waitcnt lgkmcnt(0)" ::: "memory");  // wave-local LDS RAW
#pragma unroll
      for (int q2 = 0; q2 < 4; ++q2) {
        int cc = q2 * 64 + lane;
        int row = cc >> 1, part = cc & 1;     // d-row 0..127, 16B half
        uint4 val = *(uint4*)&myvs[row * 24 + part * 8];
        int vd = v0 + row;
        int hkv = vd >> 6, d = vd & 63;
        *(uint4*)&vo[((size_t)(bb * N_KVH + hkv) * 64 + d) * 2048 + token0 + part * 8] = val;
      }
    }
  } else {  // MODE 1: fp32 store (lanes in quad -> consecutive n, coalesced)
#pragma unroll
    for (int tn = 0; tn < 8; tn++) {
#pragma unroll
      for (int reg = 0; reg < 4; reg++) {
        int m = m0 + w * 16 + quad * 4 + reg;
        fo[(size_t)m * 1024 + n0 + tn * 16 + r] = acc[tn][reg];
      }
    }
  }
}

// ---------------- flash attention, sliding window, GQA ----------------
// S^T = K*Q^T (key-reduction in-lane), O^T = Vt*P^T.
// Fixed-max softmax (shift-invariant; scores bounded far below exp2 overflow):
// p = exp2(s), l accumulated IN-LANE -> zero cross-lane ops in the loop.
// XOR-swizzled LDS, double-buffered K/V staging, one barrier per tile.
// grid (32 qblocks reversed, 16 heads, 2 batch), 256 threads (4 waves x 16 queries).

__global__ __launch_bounds__(256) void attn_kernel(
    const u16* __restrict__ Q, const u16* __restrict__ K,
    const u16* __restrict__ Vt, u16* __restrict__ O) {
  __shared__ u16 k_s[2][64 * 64];
  __shared__ u16 v_s[2][64 * 64];
  __shared__ u16 pt[4][16 * 64];
  int tid = threadIdx.x, w = tid >> 6, lane = tid & 63, quad = lane >> 4, r = lane & 15;
  int qb = 31 - blockIdx.x;  // long blocks first
  int h = blockIdx.y, b = blockIdx.z;
  int i0 = qb * 64;
  int hk = h >> 2;
  int qw0 = i0 + w * 16;
  int iq = qw0 + r;

  const u16* qptr = Q + (size_t)((b * N_H + h) * N_L + iq) * HDIM;
  short8 qf[2];
  qf[0] = *(const short8*)&qptr[quad * 8];
  qf[1] = *(const short8*)&qptr[32 + quad * 8];

  const u16* kbase = K + (size_t)(b * N_KVH + hk) * N_L * HDIM;
  const u16* vtbase = Vt + (size_t)(b * N_KVH + hk) * HDIM * N_L;

  auto stage = [&](int jt, int buf) {
#pragma unroll
    for (int it = 0; it < 2; ++it) {
      int cc = it * 256 + tid;
      int row = cc >> 3, p = cc & 7, c = p ^ (row & 7);
      gl2lds16(&kbase[(size_t)(jt * 64 + row) * 64 + c * 8], &k_s[buf][cc * 8]);
    }
#pragma unroll
    for (int it = 0; it < 2; ++it) {
      int cc = it * 256 + tid;
      int row = cc >> 3, p = cc & 7, c = p ^ (row & 7);
      gl2lds16(&vtbase[(size_t)row * 2048 + jt * 64 + c * 8], &v_s[buf][cc * 8]);
    }
  };

  float l_lane = 0.f;
  f32x4 o_acc[4];
#pragma unroll
  for (int tm = 0; tm < 4; tm++) o_acc[tm] = {0.f, 0.f, 0.f, 0.f};

  int jt0 = (i0 >= WINDOW) ? ((i0 - (WINDOW - 1)) >> 6) : 0;
  int nt = qb - jt0 + 1;
  u16* mypt = pt[w];
  int rx = r & 7;

  stage(jt0, 0);

  for (int t = 0; t < nt; ++t) {
    int jt = jt0 + t, j0 = jt << 6, buf = t & 1;
    __syncthreads();  // drains vmcnt: buf's staging complete
    if (t + 1 < nt) stage(jt + 1, buf ^ 1);

    // S^T[j][i]: A = K rows (j), B = Q (i)
    f32x4 s_acc[4];
#pragma unroll
    for (int tm = 0; tm < 4; tm++) s_acc[tm] = {0.f, 0.f, 0.f, 0.f};
#pragma unroll
    for (int ks = 0; ks < 2; ks++) {
      int pc = (ks * 4 + quad) ^ rx;
#pragma unroll
      for (int tm = 0; tm < 4; tm++) {
        short8 kf = *(const short8*)&k_s[buf][(tm * 16 + r) * 64 + pc * 8];
        s_acc[tm] = __builtin_amdgcn_mfma_f32_16x16x32_bf16(kf, qf[ks], s_acc[tm], 0, 0, 0);
      }
    }

    bool interior = (j0 + 63 <= qw0) && (qw0 + 15 - j0 < WINDOW);
    if (!interior) {
#pragma unroll
      for (int tm = 0; tm < 4; tm++) {
#pragma unroll
        for (int reg = 0; reg < 4; reg++) {
          int j = j0 + tm * 16 + quad * 4 + reg;
          bool ok = (j <= iq) && (iq - j < WINDOW);
          if (!ok) s_acc[tm][reg] = -1e30f;  // exp2 -> 0
        }
      }
    }

    // fixed-max softmax: p = exp2(s), in-lane l accumulation, pack to bf16
    float p[4][4];
#pragma unroll
    for (int tm = 0; tm < 4; tm++)
#pragma unroll
      for (int reg = 0; reg < 4; reg++) {
        float e = __builtin_amdgcn_exp2f(s_acc[tm][reg]);
        p[tm][reg] = e;
        l_lane += e;
      }

    // P^T (C-layout) -> pt[i][j] swizzled, wave-local
#pragma unroll
    for (int tm = 0; tm < 4; tm++) {
      uint2 pk;
      pk.x = pk2bf(p[tm][0], p[tm][1]);
      pk.y = pk2bf(p[tm][2], p[tm][3]);
      int c = tm * 2 + (quad >> 1), half = quad & 1;
      int pp = c ^ rx;
      *(uint2*)&mypt[r * 64 + pp * 8 + half * 4] = pk;
    }
    __asm__ volatile("s_waitcnt lgkmcnt(0)" ::: "memory");  // wave-local LDS RAW

    // O^T += Vt * P^T : A = Vt rows (d), B = pt rows (i)
#pragma unroll
    for (int ks = 0; ks < 2; ks++) {
      int pc = (ks * 4 + quad) ^ rx;
      short8 bp = *(const short8*)&mypt[r * 64 + pc * 8];
#pragma unroll
      for (int tm = 0; tm < 4; tm++) {
        short8 av = *(const short8*)&v_s[buf][(tm * 16 + r) * 64 + pc * 8];
        o_acc[tm] = __builtin_amdgcn_mfma_f32_16x16x32_bf16(av, bp, o_acc[tm], 0, 0, 0);
      }
    }
  }

  // epilogue: combine l across quads (once), divide, store
  l_lane += __shfl_xor(l_lane, 16);
  l_lane += __shfl_xor(l_lane, 32);
  float inv = 1.0f / l_lane;
  size_t obase = (size_t)(b * N_L + iq) * 1024 + h * 64;
#pragma unroll
  for (int tm = 0; tm < 4; tm++) {
    uint2 pk;
    pk.x = pk2bf(o_acc[tm][0] * inv, o_acc[tm][1] * inv);
    pk.y = pk2bf(o_acc[tm][2] * inv, o_acc[tm][3] * inv);
    *(uint2*)&O[obase + tm * 16 + quad * 4] = pk;
  }
}

// ---------------- launch ----------------

extern "C" void kernel_launch(void* const* d_in, const int* in_sizes, int n_in,
                              void* d_out, int out_size, void* d_ws, size_t ws_size,
                              hipStream_t stream) {
  const float* x = (const float*)d_in[0];
  const float* Wq = (const float*)d_in[1];
  const float* Wk = (const float*)d_in[2];
  const float* Wv = (const float*)d_in[3];
  const float* Wo = (const float*)d_in[4];
  float* out = (float*)d_out;
  char* ws = (char*)d_ws;

  u16* xb    = (u16*)(ws);                // 8 MB  [4096][1024]
  u16* wqkvT = (u16*)(ws + 0x800000);     // 3 MB  [1536][1024]
  u16* woT   = (u16*)(ws + 0xB00000);     // 2 MB  [1024][1024]
  u16* Qb    = (u16*)(ws + 0xD00000);     // 8 MB  [B][H][L][64] (pre-scaled QSCALE)
  u16* Kb    = (u16*)(ws + 0x1500000);    // 2 MB  [B][KvH][L][64]
  u16* Vtb   = (u16*)(ws + 0x1700000);    // 2 MB  [B][KvH][64][L]  (transposed)
  u16* Ob    = (u16*)(ws + 0x1900000);    // 8 MB  [4096][1024]
  float* rc  = (float*)(ws + 0x2100000);  // 256 KB [2048][32]
  float* rs  = (float*)(ws + 0x2140000);  // 256 KB

  prep_kernel<<<3840, 256, 0, stream>>>(x, Wq, Wk, Wv, Wo, xb, wqkvT, woT, rc, rs);
  gemm_kernel<0><<<dim3(12, 64), 256, 0, stream>>>(xb, wqkvT, Qb, Kb, Vtb, nullptr, rc, rs);
  attn_kernel<<<dim3(32, 16, 2), 256, 0, stream>>>(Qb, Kb, Vtb, Ob);
  gemm_kernel<1><<<dim3(8, 64), 256, 0, stream>>>(Ob, woT, nullptr, nullptr, nullptr, out, nullptr, nullptr);
}

// Round 6
// 150.939 us; speedup vs baseline: 1.6350x; 1.0297x over previous
//
#include <hip/hip_runtime.h>

typedef unsigned short u16;
typedef unsigned int u32;
typedef short short8 __attribute__((ext_vector_type(8)));
typedef float f32x4 __attribute__((ext_vector_type(4)));

#define N_B 2
#define N_L 2048
#define N_D 1024
#define N_H 16
#define N_KVH 4
#define HDIM 64
#define WINDOW 1024

// log2(e) folded into Q so softmax can use exp2 directly
#define QSCALE (0.125f * 1.44269504088896f)

__device__ __forceinline__ u16 f2bf(float f) {
  unsigned u = __builtin_bit_cast(unsigned, f);
  u = u + 0x7fffu + ((u >> 16) & 1u);
  return (u16)(u >> 16);
}

// pack two f32 -> (bf16(hi)<<16)|bf16(lo), round-half-up, one v_perm
__device__ __forceinline__ u32 pk2bf(float lo, float hi) {
  u32 a = __builtin_bit_cast(u32, lo) + 0x8000u;
  u32 b = __builtin_bit_cast(u32, hi) + 0x8000u;
  return __builtin_amdgcn_perm(b, a, 0x07060302u);
}

// async global->LDS, 16B per lane. LDS dest must be wave-uniform base + lane*16.
__device__ __forceinline__ void gl2lds16(const u16* g, u16* l) {
  __builtin_amdgcn_global_load_lds((const __attribute__((address_space(1))) void*)g,
                                   (__attribute__((address_space(3))) void*)l, 16, 0, 0);
}

// ---------------- fused prep: convert x, transpose 4 weights, rope ----------------

__global__ __launch_bounds__(256) void prep_kernel(
    const float* __restrict__ x, const float* __restrict__ Wq, const float* __restrict__ Wk,
    const float* __restrict__ Wv, const float* __restrict__ Wo,
    u16* __restrict__ xb, u16* __restrict__ wqkvT, u16* __restrict__ woT,
    float* __restrict__ rc, float* __restrict__ rs) {
  __shared__ float tbuf[32][33];
  int bid = blockIdx.x, tid = threadIdx.x;
  if (bid < 1024) {  // x fp32 -> bf16, 16 elems/thread
    size_t base = ((size_t)bid * 256 + tid) * 16;
    u32 o[8];
#pragma unroll
    for (int j = 0; j < 4; j++) {
      float4 f = *(const float4*)&x[base + j * 4];
      o[2 * j] = pk2bf(f.x, f.y);
      o[2 * j + 1] = pk2bf(f.z, f.w);
    }
    *(uint4*)&xb[base] = *(uint4*)&o[0];
    *(uint4*)&xb[base + 8] = *(uint4*)&o[4];
  } else if (bid < 3584) {  // weight transposes [1024][srcN] -> [srcN][1024] bf16
    const float* src;
    u16* dst;
    int gx, t, shift;
    if (bid < 2048) { src = Wq; dst = wqkvT; gx = 32; shift = 5; t = bid - 1024; }
    else if (bid < 2304) { src = Wk; dst = wqkvT + 1024 * 1024; gx = 8; shift = 3; t = bid - 2048; }
    else if (bid < 2560) { src = Wv; dst = wqkvT + 1280 * 1024; gx = 8; shift = 3; t = bid - 2304; }
    else { src = Wo; dst = woT; gx = 32; shift = 5; t = bid - 2560; }
    int srcN = gx * 32;
    int n0 = (t & (gx - 1)) * 32, k0 = (t >> shift) * 32;
    int lx = tid & 31, ly = tid >> 5;
#pragma unroll
    for (int q = 0; q < 4; q++)
      tbuf[ly + 8 * q][lx] = src[(k0 + ly + 8 * q) * srcN + n0 + lx];
    __syncthreads();
#pragma unroll
    for (int q = 0; q < 4; q++)
      dst[(n0 + ly + 8 * q) * 1024 + k0 + lx] = f2bf(tbuf[lx][ly + 8 * q]);
  } else {  // rope tables, 2048*32
    int idx = (bid - 3584) * 256 + tid;
    int i = idx >> 5, j = idx & 31;
    float inv = powf(10000.0f, -(float)j * (1.0f / 32.0f));
    float ang = (float)i * inv;
    rc[idx] = cosf(ang);
    rs[idx] = sinf(ang);
  }
}

// ---------------- GEMM: C[M,N] = A[M,K=1024] * Bt[N,K=1024]^T ----------------
// 128x128 block, 4 waves in 2x2, each 64x64 (4x4 MFMA tiles -> 0.5 ds_read/MFMA).
// BK=64, XOR-swizzled LDS (conflict-free b128), double-buffered global_load_lds
// with ONE barrier per kt (prefetch kt+1 overlaps compute kt).
// MODE 0: qkv projection; RoPE epilogue (Q scaled by QSCALE); V stored transposed
//         globally as Vt[b][hkv][64][2048].  Grid (12, 32).
// MODE 1: out projection, fp32 store. Grid (8, 32).

template <int MODE>
__global__ __launch_bounds__(256, 2) void gemm_kernel(
    const u16* __restrict__ A, const u16* __restrict__ Bt,
    u16* __restrict__ qo, u16* __restrict__ ko, u16* __restrict__ vo,
    float* __restrict__ fo, const float* __restrict__ rc, const float* __restrict__ rs) {
  __shared__ u16 smem[65536 / 2];  // [A0|A1|B0|B1] each 128x64 u16 (8192)
  int tid = threadIdx.x;
  int w = tid >> 6, lane = tid & 63, quad = lane >> 4, r = lane & 15;
  int rx = r & 7;
  int wm = w >> 1, wn = w & 1;
  int m0 = blockIdx.y * 128, n0 = blockIdx.x * 128;

  f32x4 acc[4][4];
#pragma unroll
  for (int a_ = 0; a_ < 4; a_++)
#pragma unroll
    for (int b_ = 0; b_ < 4; b_++) acc[a_][b_] = {0.f, 0.f, 0.f, 0.f};

  // stage kt into buffer buf: A/B 128 rows x 64 elems, swizzled chunks
  auto stage = [&](int kt, int buf) {
    u16* a_s = smem + buf * 8192;
    u16* b_s = smem + 16384 + buf * 8192;
#pragma unroll
    for (int it = 0; it < 4; ++it) {
      int cc = it * 256 + tid;
      int row = cc >> 3, p = cc & 7, c = p ^ (row & 7);
      gl2lds16(&A[(size_t)(m0 + row) * 1024 + kt * 64 + c * 8], &a_s[cc * 8]);
    }
#pragma unroll
    for (int it = 0; it < 4; ++it) {
      int cc = it * 256 + tid;
      int row = cc >> 3, p = cc & 7, c = p ^ (row & 7);
      gl2lds16(&Bt[(size_t)(n0 + row) * 1024 + kt * 64 + c * 8], &b_s[cc * 8]);
    }
  };

  stage(0, 0);
  for (int kt = 0; kt < 16; ++kt) {
    int buf = kt & 1;
    __syncthreads();  // drains this buf's staging; prefetch had full compute to land
    if (kt + 1 < 16) stage(kt + 1, buf ^ 1);
    u16* a_s = smem + buf * 8192;
    u16* b_s = smem + 16384 + buf * 8192;
#pragma unroll
    for (int ks = 0; ks < 2; ks++) {
      int pc = (ks * 4 + quad) ^ rx;
      short8 af[4], bfr[4];
#pragma unroll
      for (int tm = 0; tm < 4; tm++)
        af[tm] = *(const short8*)&a_s[(wm * 64 + tm * 16 + r) * 64 + pc * 8];
#pragma unroll
      for (int tn = 0; tn < 4; tn++)
        bfr[tn] = *(const short8*)&b_s[(wn * 64 + tn * 16 + r) * 64 + pc * 8];
#pragma unroll
      for (int tm = 0; tm < 4; tm++)
#pragma unroll
        for (int tn = 0; tn < 4; tn++)
          acc[tm][tn] = __builtin_amdgcn_mfma_f32_16x16x32_bf16(af[tm], bfr[tn], acc[tm][tn], 0, 0, 0);
    }
    __syncthreads();  // compute done before buf is re-staged next iteration
  }

  int nbase = n0 + wn * 64;  // 64-aligned, uniform per wave
  if constexpr (MODE == 0) {
    if (nbase < 1024) {  // Q + RoPE + QSCALE
      int h = nbase >> 6;
#pragma unroll
      for (int tm = 0; tm < 4; tm++) {
#pragma unroll
        for (int reg = 0; reg < 4; reg++) {
          int m = m0 + wm * 64 + tm * 16 + quad * 4 + reg;
          int b = m >> 11, i = m & 2047;
          size_t base = ((size_t)(b * N_H + h) * N_L + i) * HDIM;
#pragma unroll
          for (int tn = 0; tn < 2; tn++) {
            int dlo = tn * 16 + r;
            float c = rc[i * 32 + dlo], s = rs[i * 32 + dlo];
            float vlo = acc[tm][tn][reg], vhi = acc[tm][tn + 2][reg];
            qo[base + dlo] = f2bf((vlo * c - vhi * s) * QSCALE);
            qo[base + dlo + 32] = f2bf((vhi * c + vlo * s) * QSCALE);
          }
        }
      }
    } else if (nbase < 1280) {  // K + RoPE
      int h = (nbase - 1024) >> 6;
#pragma unroll
      for (int tm = 0; tm < 4; tm++) {
#pragma unroll
        for (int reg = 0; reg < 4; reg++) {
          int m = m0 + wm * 64 + tm * 16 + quad * 4 + reg;
          int b = m >> 11, i = m & 2047;
          size_t base = ((size_t)(b * N_KVH + h) * N_L + i) * HDIM;
#pragma unroll
          for (int tn = 0; tn < 2; tn++) {
            int dlo = tn * 16 + r;
            float c = rc[i * 32 + dlo], s = rs[i * 32 + dlo];
            float vlo = acc[tm][tn][reg], vhi = acc[tm][tn + 2][reg];
            ko[base + dlo] = f2bf(vlo * c - vhi * s);
            ko[base + dlo + 32] = f2bf(vhi * c + vlo * s);
          }
        }
      }
    } else {  // V: transpose bounce reusing staging LDS -> Vt[b][hkv][64][2048]
      __syncthreads();  // all waves done reading staged tiles
      int hkv = (nbase - 1280) >> 6;
      int bb = (m0 + wm * 64) >> 11;
      int tbase = (m0 + wm * 64) & 2047;
      u16* myvs = smem + w * 4608;  // [64 d][64 tok] stride 72, 9216 B per wave
#pragma unroll
      for (int tm = 0; tm < 4; tm++) {
#pragma unroll
        for (int tn = 0; tn < 4; tn++) {
          uint2 pk;
          pk.x = pk2bf(acc[tm][tn][0], acc[tm][tn][1]);
          pk.y = pk2bf(acc[tm][tn][2], acc[tm][tn][3]);
          *(uint2*)&myvs[(tn * 16 + r) * 72 + tm * 16 + quad * 4] = pk;
        }
      }
      __asm__ volatile("s_waitcnt lgkmcnt(0)" ::: "memory");  // wave-local LDS RAW
      u16* vtb = vo + (size_t)((bb * N_KVH + hkv) * 64) * 2048;
#pragma unroll
      for (int q2 = 0; q2 < 8; ++q2) {
        int flat = q2 * 64 + lane;
        int row = flat >> 3, part = flat & 7;
        uint4 val = *(uint4*)&myvs[row * 72 + part * 8];
        *(uint4*)&vtb[row * 2048 + tbase + part * 8] = val;
      }
    }
  } else {  // MODE 1: fp32 store (quad lanes -> consecutive n, coalesced 64B)
#pragma unroll
    for (int tm = 0; tm < 4; tm++) {
#pragma unroll
      for (int reg = 0; reg < 4; reg++) {
        int m = m0 + wm * 64 + tm * 16 + quad * 4 + reg;
#pragma unroll
        for (int tn = 0; tn < 4; tn++)
          fo[(size_t)m * 1024 + nbase + tn * 16 + r] = acc[tm][tn][reg];
      }
    }
  }
}

// ---------------- flash attention, sliding window, GQA ----------------
// S^T = K*Q^T (key-reduction in-lane), O^T = Vt*P^T.
// Fixed-max softmax: p = exp2(s), l accumulated in-lane, no cross-lane in loop.
// XOR-swizzled LDS, double-buffered K/V staging, one barrier per tile.

__global__ __launch_bounds__(256) void attn_kernel(
    const u16* __restrict__ Q, const u16* __restrict__ K,
    const u16* __restrict__ Vt, u16* __restrict__ O) {
  __shared__ u16 k_s[2][64 * 64];
  __shared__ u16 v_s[2][64 * 64];
  __shared__ u16 pt[4][16 * 64];
  int tid = threadIdx.x, w = tid >> 6, lane = tid & 63, quad = lane >> 4, r = lane & 15;
  int qb = 31 - blockIdx.x;  // long blocks first
  int h = blockIdx.y, b = blockIdx.z;
  int i0 = qb * 64;
  int hk = h >> 2;
  int qw0 = i0 + w * 16;
  int iq = qw0 + r;

  const u16* qptr = Q + (size_t)((b * N_H + h) * N_L + iq) * HDIM;
  short8 qf[2];
  qf[0] = *(const short8*)&qptr[quad * 8];
  qf[1] = *(const short8*)&qptr[32 + quad * 8];

  const u16* kbase = K + (size_t)(b * N_KVH + hk) * N_L * HDIM;
  const u16* vtbase = Vt + (size_t)(b * N_KVH + hk) * HDIM * N_L;

  auto stage = [&](int jt, int buf) {
#pragma unroll
    for (int it = 0; it < 2; ++it) {
      int cc = it * 256 + tid;
      int row = cc >> 3, p = cc & 7, c = p ^ (row & 7);
      gl2lds16(&kbase[(size_t)(jt * 64 + row) * 64 + c * 8], &k_s[buf][cc * 8]);
    }
#pragma unroll
    for (int it = 0; it < 2; ++it) {
      int cc = it * 256 + tid;
      int row = cc >> 3, p = cc & 7, c = p ^ (row & 7);
      gl2lds16(&vtbase[(size_t)row * 2048 + jt * 64 + c * 8], &v_s[buf][cc * 8]);
    }
  };

  float l_lane = 0.f;
  f32x4 o_acc[4];
#pragma unroll
  for (int tm = 0; tm < 4; tm++) o_acc[tm] = {0.f, 0.f, 0.f, 0.f};

  int jt0 = (i0 >= WINDOW) ? ((i0 - (WINDOW - 1)) >> 6) : 0;
  int nt = qb - jt0 + 1;
  u16* mypt = pt[w];
  int rx = r & 7;

  stage(jt0, 0);

  for (int t = 0; t < nt; ++t) {
    int jt = jt0 + t, j0 = jt << 6, buf = t & 1;
    __syncthreads();  // drains vmcnt: buf's staging complete
    if (t + 1 < nt) stage(jt + 1, buf ^ 1);

    // S^T[j][i]: A = K rows (j), B = Q (i)
    f32x4 s_acc[4];
#pragma unroll
    for (int tm = 0; tm < 4; tm++) s_acc[tm] = {0.f, 0.f, 0.f, 0.f};
#pragma unroll
    for (int ks = 0; ks < 2; ks++) {
      int pc = (ks * 4 + quad) ^ rx;
#pragma unroll
      for (int tm = 0; tm < 4; tm++) {
        short8 kf = *(const short8*)&k_s[buf][(tm * 16 + r) * 64 + pc * 8];
        s_acc[tm] = __builtin_amdgcn_mfma_f32_16x16x32_bf16(kf, qf[ks], s_acc[tm], 0, 0, 0);
      }
    }

    bool interior = (j0 + 63 <= qw0) && (qw0 + 15 - j0 < WINDOW);
    if (!interior) {
#pragma unroll
      for (int tm = 0; tm < 4; tm++) {
#pragma unroll
        for (int reg = 0; reg < 4; reg++) {
          int j = j0 + tm * 16 + quad * 4 + reg;
          bool ok = (j <= iq) && (iq - j < WINDOW);
          if (!ok) s_acc[tm][reg] = -1e30f;  // exp2 -> 0
        }
      }
    }

    // fixed-max softmax: p = exp2(s), in-lane l accumulation, pack to bf16
    float p[4][4];
#pragma unroll
    for (int tm = 0; tm < 4; tm++)
#pragma unroll
      for (int reg = 0; reg < 4; reg++) {
        float e = __builtin_amdgcn_exp2f(s_acc[tm][reg]);
        p[tm][reg] = e;
        l_lane += e;
      }

    // P^T (C-layout) -> pt[i][j] swizzled, wave-local
#pragma unroll
    for (int tm = 0; tm < 4; tm++) {
      uint2 pk;
      pk.x = pk2bf(p[tm][0], p[tm][1]);
      pk.y = pk2bf(p[tm][2], p[tm][3]);
      int c = tm * 2 + (quad >> 1), half = quad & 1;
      int pp = c ^ rx;
      *(uint2*)&mypt[r * 64 + pp * 8 + half * 4] = pk;
    }
    __asm__ volatile("s_waitcnt lgkmcnt(0)" ::: "memory");  // wave-local LDS RAW

    // O^T += Vt * P^T : A = Vt rows (d), B = pt rows (i)
#pragma unroll
    for (int ks = 0; ks < 2; ks++) {
      int pc = (ks * 4 + quad) ^ rx;
      short8 bp = *(const short8*)&mypt[r * 64 + pc * 8];
#pragma unroll
      for (int tm = 0; tm < 4; tm++) {
        short8 av = *(const short8*)&v_s[buf][(tm * 16 + r) * 64 + pc * 8];
        o_acc[tm] = __builtin_amdgcn_mfma_f32_16x16x32_bf16(av, bp, o_acc[tm], 0, 0, 0);
      }
    }
  }

  // epilogue: combine l across quads (once), divide, store
  l_lane += __shfl_xor(l_lane, 16);
  l_lane += __shfl_xor(l_lane, 32);
  float inv = 1.0f / l_lane;
  size_t obase = (size_t)(b * N_L + iq) * 1024 + h * 64;
#pragma unroll
  for (int tm = 0; tm < 4; tm++) {
    uint2 pk;
    pk.x = pk2bf(o_acc[tm][0] * inv, o_acc[tm][1] * inv);
    pk.y = pk2bf(o_acc[tm][2] * inv, o_acc[tm][3] * inv);
    *(uint2*)&O[obase + tm * 16 + quad * 4] = pk;
  }
}

// ---------------- launch ----------------

extern "C" void kernel_launch(void* const* d_in, const int* in_sizes, int n_in,
                              void* d_out, int out_size, void* d_ws, size_t ws_size,
                              hipStream_t stream) {
  const float* x = (const float*)d_in[0];
  const float* Wq = (const float*)d_in[1];
  const float* Wk = (const float*)d_in[2];
  const float* Wv = (const float*)d_in[3];
  const float* Wo = (const float*)d_in[4];
  float* out = (float*)d_out;
  char* ws = (char*)d_ws;

  u16* xb    = (u16*)(ws);                // 8 MB  [4096][1024]
  u16* wqkvT = (u16*)(ws + 0x800000);     // 3 MB  [1536][1024]
  u16* woT   = (u16*)(ws + 0xB00000);     // 2 MB  [1024][1024]
  u16* Qb    = (u16*)(ws + 0xD00000);     // 8 MB  [B][H][L][64] (pre-scaled QSCALE)
  u16* Kb    = (u16*)(ws + 0x1500000);    // 2 MB  [B][KvH][L][64]
  u16* Vtb   = (u16*)(ws + 0x1700000);    // 2 MB  [B][KvH][64][L]  (transposed)
  u16* Ob    = (u16*)(ws + 0x1900000);    // 8 MB  [4096][1024]
  float* rc  = (float*)(ws + 0x2100000);  // 256 KB [2048][32]
  float* rs  = (float*)(ws + 0x2140000);  // 256 KB

  prep_kernel<<<3840, 256, 0, stream>>>(x, Wq, Wk, Wv, Wo, xb, wqkvT, woT, rc, rs);
  gemm_kernel<0><<<dim3(12, 32), 256, 0, stream>>>(xb, wqkvT, Qb, Kb, Vtb, nullptr, rc, rs);
  attn_kernel<<<dim3(32, 16, 2), 256, 0, stream>>>(Qb, Kb, Vtb, Ob);
  gemm_kernel<1><<<dim3(8, 32), 256, 0, stream>>>(Ob, woT, nullptr, nullptr, nullptr, out, nullptr, nullptr);
}

// Round 8
// 147.856 us; speedup vs baseline: 1.6691x; 1.0208x over previous
//
#include <hip/hip_runtime.h>

typedef unsigned short u16;
typedef unsigned int u32;
typedef short short8 __attribute__((ext_vector_type(8)));
typedef float f32x4 __attribute__((ext_vector_type(4)));

#define N_B 2
#define N_L 2048
#define N_D 1024
#define N_H 16
#define N_KVH 4
#define HDIM 64
#define WINDOW 1024

// log2(e) folded into Q so softmax can use exp2 directly
#define QSCALE (0.125f * 1.44269504088896f)

__device__ __forceinline__ u16 f2bf(float f) {
  unsigned u = __builtin_bit_cast(unsigned, f);
  u = u + 0x7fffu + ((u >> 16) & 1u);
  return (u16)(u >> 16);
}

// pack two f32 -> (bf16(hi)<<16)|bf16(lo), round-half-up, one v_perm
__device__ __forceinline__ u32 pk2bf(float lo, float hi) {
  u32 a = __builtin_bit_cast(u32, lo) + 0x8000u;
  u32 b = __builtin_bit_cast(u32, hi) + 0x8000u;
  return __builtin_amdgcn_perm(b, a, 0x07060302u);
}

// async global->LDS, 16B per lane. LDS dest must be wave-uniform base + lane*16.
__device__ __forceinline__ void gl2lds16(const u16* g, u16* l) {
  __builtin_amdgcn_global_load_lds((const __attribute__((address_space(1))) void*)g,
                                   (__attribute__((address_space(3))) void*)l, 16, 0, 0);
}

// ---------------- fused prep: convert x, transpose 4 weights, rope ----------------
// (r6 verbatim known-good version)

__global__ __launch_bounds__(256) void prep_kernel(
    const float* __restrict__ x, const float* __restrict__ Wq, const float* __restrict__ Wk,
    const float* __restrict__ Wv, const float* __restrict__ Wo,
    u16* __restrict__ xb, u16* __restrict__ wqkvT, u16* __restrict__ woT,
    float* __restrict__ rc, float* __restrict__ rs) {
  __shared__ float tbuf[32][33];
  int bid = blockIdx.x, tid = threadIdx.x;
  if (bid < 1024) {  // x fp32 -> bf16, 16 elems/thread
    size_t base = ((size_t)bid * 256 + tid) * 16;
    u32 o[8];
#pragma unroll
    for (int j = 0; j < 4; j++) {
      float4 f = *(const float4*)&x[base + j * 4];
      o[2 * j] = pk2bf(f.x, f.y);
      o[2 * j + 1] = pk2bf(f.z, f.w);
    }
    *(uint4*)&xb[base] = *(uint4*)&o[0];
    *(uint4*)&xb[base + 8] = *(uint4*)&o[4];
  } else if (bid < 3584) {  // weight transposes [1024][srcN] -> [srcN][1024] bf16
    const float* src;
    u16* dst;
    int gx, t, shift;
    if (bid < 2048) { src = Wq; dst = wqkvT; gx = 32; shift = 5; t = bid - 1024; }
    else if (bid < 2304) { src = Wk; dst = wqkvT + 1024 * 1024; gx = 8; shift = 3; t = bid - 2048; }
    else if (bid < 2560) { src = Wv; dst = wqkvT + 1280 * 1024; gx = 8; shift = 3; t = bid - 2304; }
    else { src = Wo; dst = woT; gx = 32; shift = 5; t = bid - 2560; }
    int srcN = gx * 32;
    int n0 = (t & (gx - 1)) * 32, k0 = (t >> shift) * 32;
    int lx = tid & 31, ly = tid >> 5;
#pragma unroll
    for (int q = 0; q < 4; q++)
      tbuf[ly + 8 * q][lx] = src[(k0 + ly + 8 * q) * srcN + n0 + lx];
    __syncthreads();
#pragma unroll
    for (int q = 0; q < 4; q++)
      dst[(n0 + ly + 8 * q) * 1024 + k0 + lx] = f2bf(tbuf[lx][ly + 8 * q]);
  } else {  // rope tables, 2048*32
    int idx = (bid - 3584) * 256 + tid;
    int i = idx >> 5, j = idx & 31;
    float inv = powf(10000.0f, -(float)j * (1.0f / 32.0f));
    float ang = (float)i * inv;
    rc[idx] = cosf(ang);
    rs[idx] = sinf(ang);
  }
}

// ---------------- GEMM: C[M,N] = A[M,K=1024] * Bt[N,K=1024]^T ----------------
// 128x128 block, 4 waves in 2x2, each 64x64 (4x4 MFMA tiles -> 0.5 ds_read/MFMA).
// BK=64, XOR-swizzled LDS, double-buffered global_load_lds with a SINGLE barrier
// per kt: prefetch kt+1 issued right after the barrier stays in flight across the
// whole kt compute; the next barrier's vmcnt(0) drain lands exactly when needed.
// (No WAR hazard: every wave's reads of buf complete before it passes the next
// barrier, and stage(kt+1) writes only buf^1.)
// MODE 0: qkv projection; RoPE epilogue (Q scaled by QSCALE); V stored transposed
//         globally as Vt[b][hkv][64][2048].  Grid (12, 32).
// MODE 1: out projection, fp32 store. Grid (8, 32).

template <int MODE>
__global__ __launch_bounds__(256, 2) void gemm_kernel(
    const u16* __restrict__ A, const u16* __restrict__ Bt,
    u16* __restrict__ qo, u16* __restrict__ ko, u16* __restrict__ vo,
    float* __restrict__ fo, const float* __restrict__ rc, const float* __restrict__ rs) {
  __shared__ u16 smem[65536 / 2];  // [A0|A1|B0|B1] each 128x64 u16 (8192)
  int tid = threadIdx.x;
  int w = tid >> 6, lane = tid & 63, quad = lane >> 4, r = lane & 15;
  int rx = r & 7;
  int wm = w >> 1, wn = w & 1;
  int m0 = blockIdx.y * 128, n0 = blockIdx.x * 128;

  f32x4 acc[4][4];
#pragma unroll
  for (int a_ = 0; a_ < 4; a_++)
#pragma unroll
    for (int b_ = 0; b_ < 4; b_++) acc[a_][b_] = {0.f, 0.f, 0.f, 0.f};

  // stage kt into buffer buf: A/B 128 rows x 64 elems, swizzled chunks
  auto stage = [&](int kt, int buf) {
    u16* a_s = smem + buf * 8192;
    u16* b_s = smem + 16384 + buf * 8192;
#pragma unroll
    for (int it = 0; it < 4; ++it) {
      int cc = it * 256 + tid;
      int row = cc >> 3, p = cc & 7, c = p ^ (row & 7);
      gl2lds16(&A[(size_t)(m0 + row) * 1024 + kt * 64 + c * 8], &a_s[cc * 8]);
    }
#pragma unroll
    for (int it = 0; it < 4; ++it) {
      int cc = it * 256 + tid;
      int row = cc >> 3, p = cc & 7, c = p ^ (row & 7);
      gl2lds16(&Bt[(size_t)(n0 + row) * 1024 + kt * 64 + c * 8], &b_s[cc * 8]);
    }
  };

  stage(0, 0);
  for (int kt = 0; kt < 16; ++kt) {
    int buf = kt & 1;
    __syncthreads();  // single barrier per kt: drains this buf's staging
    if (kt + 1 < 16) stage(kt + 1, buf ^ 1);
    u16* a_s = smem + buf * 8192;
    u16* b_s = smem + 16384 + buf * 8192;
#pragma unroll
    for (int ks = 0; ks < 2; ks++) {
      int pc = (ks * 4 + quad) ^ rx;
      short8 af[4], bfr[4];
#pragma unroll
      for (int tm = 0; tm < 4; tm++)
        af[tm] = *(const short8*)&a_s[(wm * 64 + tm * 16 + r) * 64 + pc * 8];
#pragma unroll
      for (int tn = 0; tn < 4; tn++)
        bfr[tn] = *(const short8*)&b_s[(wn * 64 + tn * 16 + r) * 64 + pc * 8];
#pragma unroll
      for (int tm = 0; tm < 4; tm++)
#pragma unroll
        for (int tn = 0; tn < 4; tn++)
          acc[tm][tn] = __builtin_amdgcn_mfma_f32_16x16x32_bf16(af[tm], bfr[tn], acc[tm][tn], 0, 0, 0);
    }
  }

  int nbase = n0 + wn * 64;  // 64-aligned, uniform per wave
  if constexpr (MODE == 0) {
    if (nbase < 1024) {  // Q + RoPE + QSCALE
      int h = nbase >> 6;
#pragma unroll
      for (int tm = 0; tm < 4; tm++) {
#pragma unroll
        for (int reg = 0; reg < 4; reg++) {
          int m = m0 + wm * 64 + tm * 16 + quad * 4 + reg;
          int b = m >> 11, i = m & 2047;
          size_t base = ((size_t)(b * N_H + h) * N_L + i) * HDIM;
#pragma unroll
          for (int tn = 0; tn < 2; tn++) {
            int dlo = tn * 16 + r;
            float c = rc[i * 32 + dlo], s = rs[i * 32 + dlo];
            float vlo = acc[tm][tn][reg], vhi = acc[tm][tn + 2][reg];
            qo[base + dlo] = f2bf((vlo * c - vhi * s) * QSCALE);
            qo[base + dlo + 32] = f2bf((vhi * c + vlo * s) * QSCALE);
          }
        }
      }
    } else if (nbase < 1280) {  // K + RoPE
      int h = (nbase - 1024) >> 6;
#pragma unroll
      for (int tm = 0; tm < 4; tm++) {
#pragma unroll
        for (int reg = 0; reg < 4; reg++) {
          int m = m0 + wm * 64 + tm * 16 + quad * 4 + reg;
          int b = m >> 11, i = m & 2047;
          size_t base = ((size_t)(b * N_KVH + h) * N_L + i) * HDIM;
#pragma unroll
          for (int tn = 0; tn < 2; tn++) {
            int dlo = tn * 16 + r;
            float c = rc[i * 32 + dlo], s = rs[i * 32 + dlo];
            float vlo = acc[tm][tn][reg], vhi = acc[tm][tn + 2][reg];
            ko[base + dlo] = f2bf(vlo * c - vhi * s);
            ko[base + dlo + 32] = f2bf(vhi * c + vlo * s);
          }
        }
      }
    } else {  // V: transpose bounce reusing staging LDS -> Vt[b][hkv][64][2048]
      __syncthreads();  // all waves done reading staged tiles
      int hkv = (nbase - 1280) >> 6;
      int bb = (m0 + wm * 64) >> 11;
      int tbase = (m0 + wm * 64) & 2047;
      u16* myvs = smem + w * 4608;  // [64 d][64 tok] stride 72, 9216 B per wave
#pragma unroll
      for (int tm = 0; tm < 4; tm++) {
#pragma unroll
        for (int tn = 0; tn < 4; tn++) {
          uint2 pk;
          pk.x = pk2bf(acc[tm][tn][0], acc[tm][tn][1]);
          pk.y = pk2bf(acc[tm][tn][2], acc[tm][tn][3]);
          *(uint2*)&myvs[(tn * 16 + r) * 72 + tm * 16 + quad * 4] = pk;
        }
      }
      __asm__ volatile("s_waitcnt lgkmcnt(0)" ::: "memory");  // wave-local LDS RAW
      u16* vtb = vo + (size_t)((bb * N_KVH + hkv) * 64) * 2048;
#pragma unroll
      for (int q2 = 0; q2 < 8; ++q2) {
        int flat = q2 * 64 + lane;
        int row = flat >> 3, part = flat & 7;
        uint4 val = *(uint4*)&myvs[row * 72 + part * 8];
        *(uint4*)&vtb[row * 2048 + tbase + part * 8] = val;
      }
    }
  } else {  // MODE 1: fp32 store (quad lanes -> consecutive n, coalesced 64B)
#pragma unroll
    for (int tm = 0; tm < 4; tm++) {
#pragma unroll
      for (int reg = 0; reg < 4; reg++) {
        int m = m0 + wm * 64 + tm * 16 + quad * 4 + reg;
#pragma unroll
        for (int tn = 0; tn < 4; tn++)
          fo[(size_t)m * 1024 + nbase + tn * 16 + r] = acc[tm][tn][reg];
      }
    }
  }
}

// ---------------- flash attention, sliding window, GQA ----------------
// S^T = K*Q^T (key-reduction in-lane), O^T = Vt*P^T.
// Fixed-max softmax: p = exp2(s), l accumulated in-lane, no cross-lane in loop.
// XOR-swizzled LDS, double-buffered K/V staging, one barrier per tile.

__global__ __launch_bounds__(256) void attn_kernel(
    const u16* __restrict__ Q, const u16* __restrict__ K,
    const u16* __restrict__ Vt, u16* __restrict__ O) {
  __shared__ u16 k_s[2][64 * 64];
  __shared__ u16 v_s[2][64 * 64];
  __shared__ u16 pt[4][16 * 64];
  int tid = threadIdx.x, w = tid >> 6, lane = tid & 63, quad = lane >> 4, r = lane & 15;
  int qb = 31 - blockIdx.x;  // long blocks first
  int h = blockIdx.y, b = blockIdx.z;
  int i0 = qb * 64;
  int hk = h >> 2;
  int qw0 = i0 + w * 16;
  int iq = qw0 + r;

  const u16* qptr = Q + (size_t)((b * N_H + h) * N_L + iq) * HDIM;
  short8 qf[2];
  qf[0] = *(const short8*)&qptr[quad * 8];
  qf[1] = *(const short8*)&qptr[32 + quad * 8];

  const u16* kbase = K + (size_t)(b * N_KVH + hk) * N_L * HDIM;
  const u16* vtbase = Vt + (size_t)(b * N_KVH + hk) * HDIM * N_L;

  auto stage = [&](int jt, int buf) {
#pragma unroll
    for (int it = 0; it < 2; ++it) {
      int cc = it * 256 + tid;
      int row = cc >> 3, p = cc & 7, c = p ^ (row & 7);
      gl2lds16(&kbase[(size_t)(jt * 64 + row) * 64 + c * 8], &k_s[buf][cc * 8]);
    }
#pragma unroll
    for (int it = 0; it < 2; ++it) {
      int cc = it * 256 + tid;
      int row = cc >> 3, p = cc & 7, c = p ^ (row & 7);
      gl2lds16(&vtbase[(size_t)row * 2048 + jt * 64 + c * 8], &v_s[buf][cc * 8]);
    }
  };

  float l_lane = 0.f;
  f32x4 o_acc[4];
#pragma unroll
  for (int tm = 0; tm < 4; tm++) o_acc[tm] = {0.f, 0.f, 0.f, 0.f};

  int jt0 = (i0 >= WINDOW) ? ((i0 - (WINDOW - 1)) >> 6) : 0;
  int nt = qb - jt0 + 1;
  u16* mypt = pt[w];
  int rx = r & 7;

  stage(jt0, 0);

  for (int t = 0; t < nt; ++t) {
    int jt = jt0 + t, j0 = jt << 6, buf = t & 1;
    __syncthreads();  // drains vmcnt: buf's staging complete
    if (t + 1 < nt) stage(jt + 1, buf ^ 1);

    // S^T[j][i]: A = K rows (j), B = Q (i)
    f32x4 s_acc[4];
#pragma unroll
    for (int tm = 0; tm < 4; tm++) s_acc[tm] = {0.f, 0.f, 0.f, 0.f};
#pragma unroll
    for (int ks = 0; ks < 2; ks++) {
      int pc = (ks * 4 + quad) ^ rx;
#pragma unroll
      for (int tm = 0; tm < 4; tm++) {
        short8 kf = *(const short8*)&k_s[buf][(tm * 16 + r) * 64 + pc * 8];
        s_acc[tm] = __builtin_amdgcn_mfma_f32_16x16x32_bf16(kf, qf[ks], s_acc[tm], 0, 0, 0);
      }
    }

    bool interior = (j0 + 63 <= qw0) && (qw0 + 15 - j0 < WINDOW);
    if (!interior) {
#pragma unroll
      for (int tm = 0; tm < 4; tm++) {
#pragma unroll
        for (int reg = 0; reg < 4; reg++) {
          int j = j0 + tm * 16 + quad * 4 + reg;
          bool ok = (j <= iq) && (iq - j < WINDOW);
          if (!ok) s_acc[tm][reg] = -1e30f;  // exp2 -> 0
        }
      }
    }

    // fixed-max softmax: p = exp2(s), in-lane l accumulation, pack to bf16
    float p[4][4];
#pragma unroll
    for (int tm = 0; tm < 4; tm++)
#pragma unroll
      for (int reg = 0; reg < 4; reg++) {
        float e = __builtin_amdgcn_exp2f(s_acc[tm][reg]);
        p[tm][reg] = e;
        l_lane += e;
      }

    // P^T (C-layout) -> pt[i][j] swizzled, wave-local
#pragma unroll
    for (int tm = 0; tm < 4; tm++) {
      uint2 pk;
      pk.x = pk2bf(p[tm][0], p[tm][1]);
      pk.y = pk2bf(p[tm][2], p[tm][3]);
      int c = tm * 2 + (quad >> 1), half = quad & 1;
      int pp = c ^ rx;
      *(uint2*)&mypt[r * 64 + pp * 8 + half * 4] = pk;
    }
    __asm__ volatile("s_waitcnt lgkmcnt(0)" ::: "memory");  // wave-local LDS RAW

    // O^T += Vt * P^T : A = Vt rows (d), B = pt rows (i)
#pragma unroll
    for (int ks = 0; ks < 2; ks++) {
      int pc = (ks * 4 + quad) ^ rx;
      short8 bp = *(const short8*)&mypt[r * 64 + pc * 8];
#pragma unroll
      for (int tm = 0; tm < 4; tm++) {
        short8 av = *(const short8*)&v_s[buf][(tm * 16 + r) * 64 + pc * 8];
        o_acc[tm] = __builtin_amdgcn_mfma_f32_16x16x32_bf16(av, bp, o_acc[tm], 0, 0, 0);
      }
    }
  }

  // epilogue: combine l across quads (once), divide, store
  l_lane += __shfl_xor(l_lane, 16);
  l_lane += __shfl_xor(l_lane, 32);
  float inv = 1.0f / l_lane;
  size_t obase = (size_t)(b * N_L + iq) * 1024 + h * 64;
#pragma unroll
  for (int tm = 0; tm < 4; tm++) {
    uint2 pk;
    pk.x = pk2bf(o_acc[tm][0] * inv, o_acc[tm][1] * inv);
    pk.y = pk2bf(o_acc[tm][2] * inv, o_acc[tm][3] * inv);
    *(uint2*)&O[obase + tm * 16 + quad * 4] = pk;
  }
}

// ---------------- launch ----------------

extern "C" void kernel_launch(void* const* d_in, const int* in_sizes, int n_in,
                              void* d_out, int out_size, void* d_ws, size_t ws_size,
                              hipStream_t stream) {
  const float* x = (const float*)d_in[0];
  const float* Wq = (const float*)d_in[1];
  const float* Wk = (const float*)d_in[2];
  const float* Wv = (const float*)d_in[3];
  const float* Wo = (const float*)d_in[4];
  float* out = (float*)d_out;
  char* ws = (char*)d_ws;

  u16* xb    = (u16*)(ws);                // 8 MB  [4096][1024]
  u16* wqkvT = (u16*)(ws + 0x800000);     // 3 MB  [1536][1024]
  u16* woT   = (u16*)(ws + 0xB00000);     // 2 MB  [1024][1024]
  u16* Qb    = (u16*)(ws + 0xD00000);     // 8 MB  [B][H][L][64] (pre-scaled QSCALE)
  u16* Kb    = (u16*)(ws + 0x1500000);    // 2 MB  [B][KvH][L][64]
  u16* Vtb   = (u16*)(ws + 0x1700000);    // 2 MB  [B][KvH][64][L]  (transposed)
  u16* Ob    = (u16*)(ws + 0x1900000);    // 8 MB  [4096][1024]
  float* rc  = (float*)(ws + 0x2100000);  // 256 KB [2048][32]
  float* rs  = (float*)(ws + 0x2140000);  // 256 KB

  prep_kernel<<<3840, 256, 0, stream>>>(x, Wq, Wk, Wv, Wo, xb, wqkvT, woT, rc, rs);
  gemm_kernel<0><<<dim3(12, 32), 256, 0, stream>>>(xb, wqkvT, Qb, Kb, Vtb, nullptr, rc, rs);
  attn_kernel<<<dim3(32, 16, 2), 256, 0, stream>>>(Qb, Kb, Vtb, Ob);
  gemm_kernel<1><<<dim3(8, 32), 256, 0, stream>>>(Ob, woT, nullptr, nullptr, nullptr, out, nullptr, nullptr);
}